// Round 14
// baseline (67.310 us; speedup 1.0000x reference)
//
#include <hip/hip_runtime.h>

#define EPSLN 1e-5f
#define KMINC 9

typedef _Float16 h2 __attribute__((ext_vector_type(2)));
typedef _Float16 h4 __attribute__((ext_vector_type(4)));
typedef _Float16 h8 __attribute__((ext_vector_type(8)));
typedef float f32x4 __attribute__((ext_vector_type(4)));

__device__ __forceinline__ h2 mk2(float a, float b){
  h2 v; v[0]=(_Float16)a; v[1]=(_Float16)b; return v;
}
__device__ __forceinline__ unsigned h2bits(h2 v){
  union { h2 h; unsigned u; } c; c.h = v; return c.u;
}
__device__ __forceinline__ h8 asH8(uint4 u){
  union { uint4 u; h8 h; } c; c.u = u; return c.h;
}

__device__ __forceinline__ float wred64(float v){
  #pragma unroll
  for (int m=1;m<64;m<<=1) v += __shfl_xor(v,m,64);
  return v;
}
__device__ __forceinline__ float wred32(float v){
  #pragma unroll
  for (int m=1;m<32;m<<=1) v += __shfl_xor(v,m,64);
  return v;
}

// ws word-offsets
#define WS_NODE   0            // 16384 f32
#define WS_M0B    16384        // 8192 f32
#define WS_CNT    24576        // 512 i32
#define WS_MASK   25088        // 512*8 u32 mask bitmaps
#define WS_PART   29184        // 512*4*28 f32 = 57344 -> ends 86528
#define WS_PACKW  86528        // 3328 u32 weights + 160 f32 consts

// packW (u32 words), f16 B-operand layout [col][k], XOR swizzle baked (r12-verified):
//  [0,2048)    GwB  = diag(g_pair)@We  [32][128k]
//  [2048,2560) GwaB = diag(g_edge)@Wa  [32][32k]
//  [2560,2816) W0aB = W0 rows 0..31    [16][32k]
//  [2816,3072) W0cB = W0 rows 64..95   [16][32k]
//  [3072,3328) WcB  = [Wc1|Wc2|0pad]   [16][32k]
//  f32: [3328) waD[32], [3360) gw[32], [3392) bw[32], [3424) gwa[32], [3456) bwa[32]

// ---------------- Kernel N: msa-LN/attn/node + m0b + top-k mask BITMAP + weight fold ----------------
// grid = B*L (512), block = 512 (8 waves)
__global__ __launch_bounds__(512) void k_node(
    const float* __restrict__ msa, const float* __restrict__ seq1hot,
    const float* __restrict__ xyz, const int* __restrict__ idxp,
    const int* __restrict__ topk,
    const float* __restrict__ g_msa, const float* __restrict__ b_msa,
    const float* __restrict__ g_pair, const float* __restrict__ b_pair,
    const float* __restrict__ Wq, const float* __restrict__ bq,
    const float* __restrict__ Wk, const float* __restrict__ bk,
    const float* __restrict__ Wx, const float* __restrict__ bx,
    const float* __restrict__ g_node, const float* __restrict__ b_node,
    const float* __restrict__ We, const float* __restrict__ be,
    const float* __restrict__ g_edge, const float* __restrict__ b_edge,
    const float* __restrict__ Wa, const float* __restrict__ ba,
    const float* __restrict__ W0, const float* __restrict__ b0,
    const float* __restrict__ Wc1, const float* __restrict__ Wc2,
    float* __restrict__ node, int* __restrict__ cntG, unsigned* __restrict__ maskG,
    float* __restrict__ m0bG, unsigned* __restrict__ packW)
{
  const int bid = blockIdx.x;          // b*256 + l  (l == i)
  const int b = bid >> 8;
  const int tid = threadIdx.x;
  const int w = tid >> 6, lane = tid & 63;

  __shared__ float mn[32][64];
  __shared__ float qS[64];
  __shared__ float scS[32];
  __shared__ float redS[8][64];
  __shared__ float ssumS[8];
  __shared__ float nodeS[32];
  __shared__ alignas(16) float Dv[256];
  __shared__ int   wsum[4];

  // ---- block 0: LN-folded weight packing (r12-verified) ----
  if (bid==0){
    for (int i=tid;i<2048;i+=512){
      int col=i>>6, wd=i&63, m=wd^((col&7)<<2), k0=2*m;
      packW[i] = h2bits(mk2(g_pair[k0]*We[k0*32+col], g_pair[k0+1]*We[(k0+1)*32+col]));
    }
    if (tid<512){
      int i=tid, col=i>>4, wd=i&15, m=wd^((col&3)<<2), k0=2*m;
      packW[2048+i] = h2bits(mk2(g_edge[k0]*Wa[k0*32+col], g_edge[k0+1]*Wa[(k0+1)*32+col]));
    }
    if (tid<256){
      int i=tid, col=i>>4, wd=i&15, m=wd^((col&3)<<2), k0=2*m;
      packW[2560+i] = h2bits(mk2(W0[k0*16+col], W0[(k0+1)*16+col]));
      packW[2816+i] = h2bits(mk2(W0[(64+k0)*16+col], W0[(65+k0)*16+col]));
      float lo = (col<3)? Wc1[k0*3+col] : (col<12? Wc2[k0*9+(col-3)] : 0.f);
      float hi = (col<3)? Wc1[(k0+1)*3+col] : (col<12? Wc2[(k0+1)*9+(col-3)] : 0.f);
      packW[3072+i] = h2bits(mk2(lo,hi));
    }
    if (tid<32){
      float* pf = (float*)packW;
      pf[3328+tid] = Wa[32*32+tid];                       // waD
      float gw=0.f, bw=0.f;
      for (int k=0;k<128;k++){
        gw += g_pair[k]*We[k*32+tid];
        bw += b_pair[k]*We[k*32+tid];
      }
      pf[3360+tid] = gw;
      pf[3392+tid] = bw + be[tid];
      float gwa=0.f, bwa=0.f;
      for (int c=0;c<32;c++){
        gwa += g_edge[c]*Wa[c*32+tid];
        bwa += b_edge[c]*Wa[c*32+tid];
      }
      pf[3424+tid] = gwa;
      pf[3456+tid] = bwa + ba[tid];
    }
  }

  // ---- msa LN ----
  const float gm = g_msa[lane], bm = b_msa[lane];
  for (int nn=w; nn<32; nn+=8){
    float x = msa[(size_t)(((b*32+nn)<<8)+(bid&255))*64 + lane];
    float s = wred64(x), s2 = wred64(x*x);
    float mu = s*(1.f/64.f);
    float var = s2*(1.f/64.f) - mu*mu;
    mn[nn][lane] = (x-mu)*rsqrtf(var+EPSLN)*gm + bm;
  }
  __syncthreads();
  {
    float p = (w==0)? bq[lane] : 0.f;
    for (int d=w*8; d<w*8+8; d++) p += mn[0][d]*Wq[d*64+lane];
    redS[w][lane] = p;
  }
  __syncthreads();
  if (w==0){
    float q = 0.f;
    #pragma unroll
    for (int k=0;k<8;k++) q += redS[k][lane];
    qS[lane] = q*0.125f;
  }
  __syncthreads();
  {
    float p = 0.f;
    for (int e=w*8; e<w*8+8; e++) p += Wk[lane*64+e]*qS[e];
    redS[w][lane] = p;
  }
  __syncthreads();
  float qk = 0.f;
  #pragma unroll
  for (int k=0;k<8;k++) qk += redS[k][lane];
  const float qb_ = wred64(qS[lane]*bk[lane]);
  for (int nn=w*4; nn<w*4+4; nn++){
    float p = wred64(mn[nn][lane]*qk);
    if (lane==0) scS[nn] = p + qb_;
  }
  __syncthreads();
  float mx = -1e30f;
  for (int nn=0; nn<32; nn++) mx = fmaxf(mx, scS[nn]);
  float ps=0.f, pm=0.f;
  for (int nn=w*4; nn<w*4+4; nn++){
    float e = expf(scS[nn]-mx);
    ps += e; pm += e*mn[nn][lane];
  }
  redS[w][lane] = pm;
  if (lane==0) ssumS[w] = ps;
  __syncthreads();
  if (w==0){
    float ssum = 0.f, acc = 0.f;
    #pragma unroll
    for (int k=0;k<8;k++){ ssum += ssumS[k]; acc += redS[k][lane]; }
    qS[lane] = acc / ssum;
  }
  __syncthreads();
  if (tid<32){
    float acc = bx[tid];
    for (int k=0;k<64;k++) acc += qS[k]*Wx[k*32+tid];
    const float* s1 = &seq1hot[bid*21];
    for (int k=0;k<21;k++) acc += s1[k]*Wx[(64+k)*32+tid];
    float s = wred32(acc), s2 = wred32(acc*acc);
    float mu = s*(1.f/32.f), var = s2*(1.f/32.f)-mu*mu;
    float v = (acc-mu)*rsqrtf(var+EPSLN)*g_node[tid] + b_node[tid];
    node[bid*32+tid] = v;
    nodeS[tid] = v;
  }
  __syncthreads();
  if (tid<16){
    float acc = b0[tid];
    for (int k=0;k<32;k++) acc += nodeS[k]*W0[(32+k)*16+tid];
    m0bG[bid*16+tid] = acc;
  }

  // --- Phase 2: exact stable top-k rank -> mask BITMAP (tid<256, thread=j) ---
  const bool act = tid < 256;
  const int i = bid & 255;
  const int j = tid;
  float D = 0.f;
  if (act){
    const float cax = xyz[(bid*3+1)*3+0];
    const float cay = xyz[(bid*3+1)*3+1];
    const float caz = xyz[(bid*3+1)*3+2];
    const int jb = (b<<8)+j;
    float dx = xyz[(jb*3+1)*3+0]-cax;
    float dy = xyz[(jb*3+1)*3+1]-cay;
    float dz = xyz[(jb*3+1)*3+2]-caz;
    D = sqrtf(dx*dx+dy*dy+dz*dz) + (i==j ? 999.9f : 0.f);
  }
  __syncthreads();
  if (act) Dv[j] = D;
  __syncthreads();
  bool m = false;
  if (act){
    int rank = 0;
    for (int j2=0;j2<256;j2+=4){
      const float4 dv = *(const float4*)&Dv[j2];
      rank += (dv.x < D || (dv.x == D && (j2+0) < j)) ? 1 : 0;
      rank += (dv.y < D || (dv.y == D && (j2+1) < j)) ? 1 : 0;
      rank += (dv.z < D || (dv.z == D && (j2+2) < j)) ? 1 : 0;
      rank += (dv.w < D || (dv.w == D && (j2+3) < j)) ? 1 : 0;
    }
    int K = topk[0];
    if (K<=0 || K>256){
      float f = ((const float*)topk)[0];
      K = (f>=1.f && f<=256.f) ? (int)f : 64;
    }
    const int sep = abs(idxp[(b<<8)+j] - idxp[bid]);
    m = (rank < K) || (i!=j && sep < KMINC);
  }
  unsigned long long bal = __ballot(m);       // all-false for waves 4..7
  if (act && (j&63)==0){
    const int wv = j >> 6;
    maskG[bid*8 + wv*2]   = (unsigned)bal;
    maskG[bid*8 + wv*2+1] = (unsigned)(bal>>32);
    wsum[wv] = __popcll(bal);
  }
  __syncthreads();
  if (tid==0) cntG[bid] = wsum[0]+wsum[1]+wsum[2]+wsum[3];
}

// ---------------- Kernel S: STREAMING pair pipeline — block = (item, 64-j chunk) ----------------
// grid = 2048 (512 items x 4 chunks), block = 256 (4 waves; wave = 16-row M-tile).
// Contiguous 32KB pair read per block; ALL rows computed; mask bit gates accumulation.
// r12-verified MFMA chain + LN folds. 2 barriers. Partials -> ws (k_fin reduces).
__global__ __launch_bounds__(256) void k_pair(
    const float* __restrict__ pair, const float* __restrict__ xyz,
    const float* __restrict__ node, const unsigned* __restrict__ maskG,
    const float* __restrict__ m0bG, const unsigned* __restrict__ packW,
    float* __restrict__ part)
{
  const int tid = threadIdx.x;
  const int w   = tid >> 6;         // wave 0..3
  const int L   = tid & 63;
  const int h   = L >> 5;
  const int l32 = L & 31;
  const int q   = L >> 4;
  const int cl  = L & 15;

  __shared__ alignas(16) unsigned char GwB[8192];
  __shared__ alignas(16) unsigned char GwaB[2048];
  __shared__ alignas(16) unsigned char W0aB[1024];
  __shared__ alignas(16) unsigned char W0cB[1024];
  __shared__ alignas(16) unsigned char WcB[1024];
  __shared__ float waDS[32], gwS[32], bwS[32], gwaS[32], bwaS[32];
  __shared__ float m0bS[16];
  __shared__ unsigned maskS[8];
  __shared__ alignas(16) unsigned char pnB[64*256];   // raw pair rows f16, swz (slot&7)<<4
  __shared__ alignas(16) unsigned char ndB[64*64];    // node_j f16, swz (slot&3)<<4
  __shared__ alignas(16) unsigned char eB [64*64];
  __shared__ alignas(16) unsigned char aB [64*64];
  __shared__ float rsS[64], rmS[64];
  __shared__ float geoS[64][4];
  __shared__ float xjS[64][9];
  __shared__ float cS[64*12];
  __shared__ float pstS[4][16];
  __shared__ float pofS[4][9];

  const int item  = blockIdx.x >> 2;
  const int chunk = blockIdx.x & 3;
  const int j0    = chunk*64;
  const int b     = item >> 8;

  // ---- prologue ----
  for (int i2=tid;i2<2048;i2+=256) ((unsigned*)GwB)[i2] = packW[i2];
  for (int i2=tid;i2<512; i2+=256) ((unsigned*)GwaB)[i2]= packW[2048+i2];
  if (tid<256){
    ((unsigned*)W0aB)[tid] = packW[2560+tid];
    ((unsigned*)W0cB)[tid] = packW[2816+tid];
    ((unsigned*)WcB)[tid]  = packW[3072+tid];
  }
  if (tid<160){
    const float* pf = (const float*)packW;
    float v = pf[3328+tid];
    if (tid<32) waDS[tid]=v;
    else if (tid<64) gwS[tid-32]=v;
    else if (tid<96) bwS[tid-64]=v;
    else if (tid<128) gwaS[tid-96]=v;
    else bwaS[tid-128]=v;
  }
  if (tid>=160 && tid<176) m0bS[tid-160] = m0bG[item*16 + (tid-160)];
  if (tid>=176 && tid<184) maskS[tid-176] = maskG[item*8 + (tid-176)];
  __syncthreads();

  const float cax = xyz[(item*3+1)*3+0];
  const float cay = xyz[(item*3+1)*3+1];
  const float caz = xyz[(item*3+1)*3+2];

  // ---- prefetch 8 pair rows + node vals (contiguous streaming) ----
  float4 pv[8]; float nv[8];
  #pragma unroll
  for (int it=0; it<8; ++it){
    const int slot = 16*w + 2*it + h;
    const int jb = (b<<8) + j0 + slot;
    pv[it] = *(const float4*)&pair[(((long)item*256 + j0 + slot)*128) + l32*4];
    nv[it] = node[jb*32 + l32];
  }
  // ---- stage + LN1 stats ----
  #pragma unroll
  for (int it=0; it<8; ++it){
    const int slot = 16*w + 2*it + h;
    const int jb = (b<<8) + j0 + slot;
    const float4 pv4 = pv[it];
    if (l32<9) xjS[slot][l32] = xyz[(size_t)jb*9 + l32];
    float sm  = pv4.x+pv4.y+pv4.z+pv4.w;
    float sm2 = pv4.x*pv4.x+pv4.y*pv4.y+pv4.z*pv4.z+pv4.w*pv4.w;
    #pragma unroll
    for (int mm=1;mm<32;mm<<=1){ sm += __shfl_xor(sm,mm,64); sm2 += __shfl_xor(sm2,mm,64); }
    const float mu = sm*(1.f/128.f);
    const float var = sm2*(1.f/128.f)-mu*mu;
    const float rs = rsqrtf(var+EPSLN);
    h4 o; o[0]=(_Float16)pv4.x; o[1]=(_Float16)pv4.y; o[2]=(_Float16)pv4.z; o[3]=(_Float16)pv4.w;
    *(h4*)&pnB[slot*256 + ((l32*8) ^ ((slot&7)<<4))] = o;
    *(_Float16*)&ndB[slot*64 + ((l32*2) ^ ((slot&3)<<4))] = (_Float16)nv[it];
    if (l32==0){
      rsS[slot]=rs; rmS[slot]=rs*mu;
      float jx = xyz[(size_t)jb*9+3]-cax;
      float jy = xyz[(size_t)jb*9+4]-cay;
      float jz = xyz[(size_t)jb*9+5]-caz;
      geoS[slot][0]=jx; geoS[slot][1]=jy; geoS[slot][2]=jz;
      geoS[slot][3]=sqrtf(jx*jx+jy*jy+jz*jz);
    }
  }

  const int sA = 16*w + cl;

  // ---- GEMM1: E = P @ Gw ----
  f32x4 accE0 = {0.f,0.f,0.f,0.f}, accE1 = {0.f,0.f,0.f,0.f};
  #pragma unroll
  for (int s=0;s<4;++s){
    const h8 af  = asH8(*(const uint4*)&pnB[sA*256 + ((s*64 + q*16) ^ ((sA&7)<<4))]);
    const h8 b0f = asH8(*(const uint4*)&GwB[cl*256 + ((s*64 + q*16) ^ ((cl&7)<<4))]);
    const h8 b1f = asH8(*(const uint4*)&GwB[(16+cl)*256 + ((s*64 + q*16) ^ (((16+cl)&7)<<4))]);
    accE0 = __builtin_amdgcn_mfma_f32_16x16x32_f16(af, b0f, accE0, 0,0,0);
    accE1 = __builtin_amdgcn_mfma_f32_16x16x32_f16(af, b1f, accE1, 0,0,0);
  }

  // ---- LN1 fold -> E raw; LN2 stats ----
  float mu2[4], rs2v[4];
  #pragma unroll
  for (int reg=0;reg<4;++reg){
    const int sr = 16*w + q*4 + reg;
    const float rs1 = rsS[sr], rm1 = rmS[sr];
    const float E0 = rs1*accE0[reg] - rm1*gwS[cl]    + bwS[cl];
    const float E1 = rs1*accE1[reg] - rm1*gwS[16+cl] + bwS[16+cl];
    float s1 = E0+E1, s2 = E0*E0+E1*E1;
    #pragma unroll
    for (int mm=1;mm<16;mm<<=1){ s1 += __shfl_xor(s1,mm,64); s2 += __shfl_xor(s2,mm,64); }
    const float mu = s1*(1.f/32.f);
    const float var = s2*(1.f/32.f)-mu*mu;
    rs2v[reg] = rsqrtf(var+EPSLN);
    mu2[reg]  = mu;
    *(_Float16*)&eB[sr*64 + ((2*cl) ^ ((sr&3)<<4))]      = (_Float16)E0;
    *(_Float16*)&eB[sr*64 + ((2*(16+cl)) ^ ((sr&3)<<4))] = (_Float16)E1;
  }

  // ---- GEMM2 + fold2 + relu -> aB ----
  {
    const h8 eaf = asH8(*(const uint4*)&eB[sA*64 + ((q*16) ^ ((sA&3)<<4))]);
    const h8 gb0 = asH8(*(const uint4*)&GwaB[cl*64 + ((q*16) ^ ((cl&3)<<4))]);
    const h8 gb1 = asH8(*(const uint4*)&GwaB[(16+cl)*64 + ((q*16) ^ (((16+cl)&3)<<4))]);
    f32x4 z = {0.f,0.f,0.f,0.f};
    f32x4 accA0 = __builtin_amdgcn_mfma_f32_16x16x32_f16(eaf, gb0, z, 0,0,0);
    f32x4 accA1 = __builtin_amdgcn_mfma_f32_16x16x32_f16(eaf, gb1, z, 0,0,0);
    #pragma unroll
    for (int reg=0;reg<4;++reg){
      const int sr = 16*w + q*4 + reg;
      const float dist = geoS[sr][3];
      const float a0 = fmaxf(rs2v[reg]*accA0[reg] - rs2v[reg]*mu2[reg]*gwaS[cl]
                             + bwaS[cl] + dist*waDS[cl], 0.f);
      const float a1 = fmaxf(rs2v[reg]*accA1[reg] - rs2v[reg]*mu2[reg]*gwaS[16+cl]
                             + bwaS[16+cl] + dist*waDS[16+cl], 0.f);
      *(_Float16*)&aB[sr*64 + ((2*cl) ^ ((sr&3)<<4))]      = (_Float16)a0;
      *(_Float16*)&aB[sr*64 + ((2*(16+cl)) ^ ((sr&3)<<4))] = (_Float16)a1;
    }
  }

  // ---- GEMM3 (state) + GEMM4 (c), mask-gated accumulation ----
  float stP = 0.f;
  {
    const h8 aaf = asH8(*(const uint4*)&aB[sA*64 + ((q*16) ^ ((sA&3)<<4))]);
    const h8 naf = asH8(*(const uint4*)&ndB[sA*64 + ((q*16) ^ ((sA&3)<<4))]);
    const h8 wa0 = asH8(*(const uint4*)&W0aB[cl*64 + ((q*16) ^ ((cl&3)<<4))]);
    const h8 wc0 = asH8(*(const uint4*)&W0cB[cl*64 + ((q*16) ^ ((cl&3)<<4))]);
    const h8 wcf = asH8(*(const uint4*)&WcB[cl*64 + ((q*16) ^ ((cl&3)<<4))]);
    f32x4 z = {0.f,0.f,0.f,0.f};
    f32x4 accM = __builtin_amdgcn_mfma_f32_16x16x32_f16(naf, wc0, z, 0,0,0);
    accM = __builtin_amdgcn_mfma_f32_16x16x32_f16(aaf, wa0, accM, 0,0,0);
    f32x4 accC = __builtin_amdgcn_mfma_f32_16x16x32_f16(aaf, wcf, z, 0,0,0);
    #pragma unroll
    for (int reg=0;reg<4;++reg){
      const int sr = 16*w + q*4 + reg;
      const int jg = j0 + sr;
      const bool mb = (maskS[jg>>5] >> (jg&31)) & 1;
      if (mb) stP += fmaxf(accM[reg] + m0bS[cl], 0.f);
      if (cl < 12) cS[sr*12 + cl] = accC[reg];
    }
  }
  stP += __shfl_xor(stP, 16, 64);
  stP += __shfl_xor(stP, 32, 64);
  if (L < 16) pstS[w][L] = stP;

  // ---- offsets: halves x 8 slots, lanes l32<9, mask-gated ----
  float ofP = 0.f;
  if (l32 < 9){
    const int o = l32/3, x = l32 - o*3;
    #pragma unroll
    for (int jc=0;jc<8;++jc){
      const int slot = 16*w + h*8 + jc;
      const int jg = j0 + slot;
      const bool mb = (maskS[jg>>5] >> (jg&31)) & 1;
      if (mb){
        const float dj = geoS[slot][3];
        const float dh = geoS[slot][x]/(dj+1e-8f);
        const float* cr = &cS[slot*12];
        float val = cr[o]*dh;
        const float caxj = xjS[slot][3+x];
        #pragma unroll
        for (int c2=0;c2<3;c2++) val += cr[3+o*3+c2]*(xjS[slot][c2*3+x]-caxj);
        ofP += val;
      }
    }
  }
  ofP += __shfl_xor(ofP, 32, 64);
  if (L < 9) pofS[w][L] = ofP;
  __syncthreads();

  // ---- write chunk partial ----
  if (tid < 64){
    float sst=0.f, sof=0.f;
    #pragma unroll
    for (int k2=0;k2<4;k2++){
      if (L<16) sst += pstS[k2][L];
      if (L<9)  sof += pofS[k2][L];
    }
    const int pbase = (item*4 + chunk)*28;
    if (L<16) part[pbase + L] = sst;
    if (L<9)  part[pbase + 16 + L] = sof;
  }
}

// ---------------- Kernel F: combine 4 chunk partials, scale by deg, form outputs ----------------
// grid = B*L (512), block = 64
__global__ __launch_bounds__(64) void k_fin(
    const float* __restrict__ xyz, const int* __restrict__ cntG,
    const float* __restrict__ part, float* __restrict__ out)
{
  const int bid = blockIdx.x;
  const int t = threadIdx.x;
  __shared__ float offF[9];
  const int n = cntG[bid];
  const float invd = 1.f/fmaxf((float)n,1.f);
  if (t<16){
    float s=0.f;
    #pragma unroll
    for (int k2=0;k2<4;k2++) s += part[(bid*4+k2)*28 + t];
    out[4608 + bid*16 + t] = s*invd;           // state
  } else if (t<25){
    float s=0.f;
    #pragma unroll
    for (int k2=0;k2<4;k2++) s += part[(bid*4+k2)*28 + t];
    offF[t-16] = s*invd;
  }
  __syncthreads();
  if (t<9){
    const int o=t/3, x=t-o*3;
    const float cac = xyz[(bid*3+1)*3+x];
    const float CA = cac + offF[3+x];          // offset[:,:,1]
    const float v = (o==1)? CA : (CA + offF[o*3+x]);
    out[bid*9 + t] = v;                        // xyz_new
  }
}

extern "C" void kernel_launch(void* const* d_in, const int* in_sizes, int n_in,
                              void* d_out, int out_size, void* d_ws, size_t ws_size,
                              hipStream_t stream)
{
  const float* msa     = (const float*)d_in[0];
  const float* pair    = (const float*)d_in[1];
  const float* xyz     = (const float*)d_in[2];
  const float* seq1hot = (const float*)d_in[3];
  const float* g_msa   = (const float*)d_in[4];
  const float* b_msa   = (const float*)d_in[5];
  const float* g_pair  = (const float*)d_in[6];
  const float* b_pair  = (const float*)d_in[7];
  const float* Wq      = (const float*)d_in[8];
  const float* bq      = (const float*)d_in[9];
  const float* Wk      = (const float*)d_in[10];
  const float* bk      = (const float*)d_in[11];
  const float* Wx      = (const float*)d_in[12];
  const float* bx      = (const float*)d_in[13];
  const float* g_node  = (const float*)d_in[14];
  const float* b_node  = (const float*)d_in[15];
  const float* We      = (const float*)d_in[16];
  const float* be      = (const float*)d_in[17];
  const float* g_edge  = (const float*)d_in[18];
  const float* b_edge  = (const float*)d_in[19];
  const float* Wa      = (const float*)d_in[20];
  const float* ba      = (const float*)d_in[21];
  const float* W0      = (const float*)d_in[22];
  const float* b0      = (const float*)d_in[23];
  const float* Wc1     = (const float*)d_in[24];
  const float* Wc2     = (const float*)d_in[25];
  const int*   idx     = (const int*)d_in[26];
  const int*   topkp   = (const int*)d_in[27];
  float* out = (float*)d_out;

  float* wsf = (float*)d_ws;
  float*    node  = wsf + WS_NODE;
  float*    m0bG  = wsf + WS_M0B;
  int*      cntG  = (int*)(wsf + WS_CNT);
  unsigned* maskG = (unsigned*)(wsf + WS_MASK);
  float*    partb = wsf + WS_PART;
  unsigned* packW = (unsigned*)(wsf + WS_PACKW);

  k_node<<<512, 512, 0, stream>>>(msa, seq1hot, xyz, idx, topkp, g_msa, b_msa,
                                  g_pair, b_pair, Wq, bq, Wk, bk, Wx, bx,
                                  g_node, b_node, We, be, g_edge, b_edge,
                                  Wa, ba, W0, b0, Wc1, Wc2,
                                  node, cntG, maskG, m0bG, packW);
  k_pair<<<2048, 256, 0, stream>>>(pair, xyz, node, maskG, m0bG, packW, partb);
  k_fin<<<512, 64, 0, stream>>>(xyz, cntG, partb, out);
}

// Round 15
// 46.302 us; speedup vs baseline: 1.4537x; 1.4537x over previous
//
#include <hip/hip_runtime.h>

#define EPSLN 1e-5f
#define KMINC 9
#define SLI   10         // slices per (b,i), 8 rows each -> covers n <= 80

typedef _Float16 h2 __attribute__((ext_vector_type(2)));
typedef _Float16 h4 __attribute__((ext_vector_type(4)));

#if defined(__has_builtin)
#if __has_builtin(__builtin_amdgcn_fdot2)
#define FDOT2(a,b,c) __builtin_amdgcn_fdot2((a),(b),(c),false)
#endif
#endif
#ifndef FDOT2
#define FDOT2(a,b,c) ((c) + (float)(a)[0]*(float)(b)[0] + (float)(a)[1]*(float)(b)[1])
#endif

__device__ __forceinline__ h2 mk2(float a, float b){
  h2 v; v[0]=(_Float16)a; v[1]=(_Float16)b; return v;
}
__device__ __forceinline__ unsigned h2bits(h2 v){
  union { h2 h; unsigned u; } c; c.h = v; return c.u;
}
__device__ __forceinline__ h2 asH2(unsigned u){
  union { unsigned u; h2 h; } c; c.u = u; return c.h;
}

__device__ __forceinline__ float wred64(float v){
  #pragma unroll
  for (int m=1;m<64;m<<=1) v += __shfl_xor(v,m,64);
  return v;
}
__device__ __forceinline__ float wred32(float v){
  #pragma unroll
  for (int m=1;m<32;m<<=1) v += __shfl_xor(v,m,64);
  return v;
}

// ws word-offsets
#define WS_NODE   0
#define WS_CNT    16384
#define WS_JLIST  16896       // 512*96 ints
#define WS_M0B    66048       // 512*16 f32
#define WS_PART   74240       // 512*SLI*28 f32 = 143360
#define WS_PACKW  217600      // q-blocked packed weights (3552 u32)

// ---------------- Kernel P: msa-LN/attention/node + m0b + top-k mask + weight packing ----------------
// grid = B*L (512), block = 512 (8 waves)
__global__ __launch_bounds__(512) void k_prep(
    const float* __restrict__ msa, const float* __restrict__ seq1hot,
    const float* __restrict__ xyz, const int* __restrict__ idxp,
    const int* __restrict__ topk,
    const float* __restrict__ g_msa, const float* __restrict__ b_msa,
    const float* __restrict__ Wq, const float* __restrict__ bq,
    const float* __restrict__ Wk, const float* __restrict__ bk,
    const float* __restrict__ Wx, const float* __restrict__ bx,
    const float* __restrict__ g_node, const float* __restrict__ b_node,
    const float* __restrict__ We, const float* __restrict__ Wa,
    const float* __restrict__ W0, const float* __restrict__ b0,
    const float* __restrict__ Wc1, const float* __restrict__ Wc2,
    float* __restrict__ node, int* __restrict__ cnt, int* __restrict__ jlist,
    float* __restrict__ m0bG, unsigned* __restrict__ packW)
{
  const int bid = blockIdx.x;          // b*256 + l  (l == i)
  const int b = bid >> 8;
  const int tid = threadIdx.x;
  const int w = tid >> 6, lane = tid & 63;   // 8 waves

  __shared__ float mn[32][64];
  __shared__ float qS[64];
  __shared__ float scS[32];
  __shared__ float redS[8][64];
  __shared__ float ssumS[8];
  __shared__ float nodeS[32];
  __shared__ alignas(16) float Dv[256];
  __shared__ int   wsum[4];

  // ---- block 0 packs weights q-blocked f16 into ws (for k_main) ----
  if (bid==0){
    for (int i=tid;i<2048;i+=512){
      int qb=i>>7, r7=i&127, t=r7>>2, i2=r7&3, q=4*qb+i2;
      packW[i] = h2bits(mk2(We[(2*q)*32+t], We[(2*q+1)*32+t]));
    }
    for (int i=tid;i<512; i+=512){
      int qb=i>>7, r7=i&127, t=r7>>2, i2=r7&3, q=4*qb+i2;
      packW[2048+i] = h2bits(mk2(Wa[(2*q)*32+t], Wa[(2*q+1)*32+t]));
    }
    for (int i=tid;i<768; i+=512){
      int qb=i>>6, r6=i&63, tc=r6>>2, i2=r6&3, q=4*qb+i2;
      packW[2560+i] = h2bits(mk2(W0[(2*q)*16+tc], W0[(2*q+1)*16+tc]));
    }
    if (tid<192){
      int qb=tid/48, r48=tid%48, tc=r48>>2, i2=r48&3, q=4*qb+i2;
      float lo = (tc<3)? Wc1[(2*q)*3+tc]   : Wc2[(2*q)*9+(tc-3)];
      float hi = (tc<3)? Wc1[(2*q+1)*3+tc] : Wc2[(2*q+1)*9+(tc-3)];
      packW[3328+tid] = h2bits(mk2(lo,hi));
    }
    if (tid<32) ((float*)packW)[3520+tid] = Wa[32*32+tid];
  }

  // ---- msa LN: wave w rows w, w+8, w+16, w+24 ----
  const float gm = g_msa[lane], bm = b_msa[lane];
  for (int nn=w; nn<32; nn+=8){
    float x = msa[(size_t)(((b*32+nn)<<8)+(bid&255))*64 + lane];
    float s = wred64(x), s2 = wred64(x*x);
    float mu = s*(1.f/64.f);
    float var = s2*(1.f/64.f) - mu*mu;
    mn[nn][lane] = (x-mu)*rsqrtf(var+EPSLN)*gm + bm;
  }
  __syncthreads();
  // ---- q[e=lane]: partial over d-range per wave ----
  {
    float p = (w==0)? bq[lane] : 0.f;
    for (int d=w*8; d<w*8+8; d++) p += mn[0][d]*Wq[d*64+lane];
    redS[w][lane] = p;
  }
  __syncthreads();
  if (w==0){
    float q = 0.f;
    #pragma unroll
    for (int k=0;k<8;k++) q += redS[k][lane];
    qS[lane] = q*0.125f;               // 1/sqrt(64)
  }
  __syncthreads();
  // ---- qk[d=lane]: partial over e-range per wave ----
  {
    float p = 0.f;
    for (int e=w*8; e<w*8+8; e++) p += Wk[lane*64+e]*qS[e];
    redS[w][lane] = p;
  }
  __syncthreads();
  float qk = 0.f;
  #pragma unroll
  for (int k=0;k<8;k++) qk += redS[k][lane];
  const float qb_ = wred64(qS[lane]*bk[lane]);
  // ---- scores: wave w rows w*4..w*4+3 ----
  for (int nn=w*4; nn<w*4+4; nn++){
    float p = wred64(mn[nn][lane]*qk);
    if (lane==0) scS[nn] = p + qb_;
  }
  __syncthreads();
  // ---- softmax + weighted msa ----
  float mx = -1e30f;
  for (int nn=0; nn<32; nn++) mx = fmaxf(mx, scS[nn]);
  float ps=0.f, pm=0.f;
  for (int nn=w*4; nn<w*4+4; nn++){
    float e = expf(scS[nn]-mx);
    ps += e; pm += e*mn[nn][lane];
  }
  redS[w][lane] = pm;
  if (lane==0) ssumS[w] = ps;
  __syncthreads();
  if (w==0){
    float ssum = 0.f, acc = 0.f;
    #pragma unroll
    for (int k=0;k<8;k++){ ssum += ssumS[k]; acc += redS[k][lane]; }
    qS[lane] = acc / ssum;
  }
  __syncthreads();
  if (tid<32){
    float acc = bx[tid];
    for (int k=0;k<64;k++) acc += qS[k]*Wx[k*32+tid];
    const float* s1 = &seq1hot[bid*21];
    for (int k=0;k<21;k++) acc += s1[k]*Wx[(64+k)*32+tid];
    float s = wred32(acc), s2 = wred32(acc*acc);
    float mu = s*(1.f/32.f), var = s2*(1.f/32.f)-mu*mu;
    float v = (acc-mu)*rsqrtf(var+EPSLN)*g_node[tid] + b_node[tid];
    node[bid*32+tid] = v;
    nodeS[tid] = v;
  }
  __syncthreads();
  if (tid<16){
    float acc = b0[tid];
    for (int k=0;k<32;k++) acc += nodeS[k]*W0[(32+k)*16+tid];
    m0bG[bid*16+tid] = acc;
  }

  // --- Phase 2: distances, exact stable top-k rank, compaction (tid<256, thread=j) ---
  const bool act = tid < 256;
  const int i = bid & 255;
  const int j = tid;
  float D = 0.f;
  if (act){
    const float cax = xyz[(bid*3+1)*3+0];
    const float cay = xyz[(bid*3+1)*3+1];
    const float caz = xyz[(bid*3+1)*3+2];
    const int jb = (b<<8)+j;
    float dx = xyz[(jb*3+1)*3+0]-cax;
    float dy = xyz[(jb*3+1)*3+1]-cay;
    float dz = xyz[(jb*3+1)*3+2]-caz;
    D = sqrtf(dx*dx+dy*dy+dz*dz) + (i==j ? 999.9f : 0.f);
  }
  __syncthreads();
  if (act) Dv[j] = D;
  __syncthreads();
  if (act){
    int rank = 0;
    for (int j2=0;j2<256;j2+=4){
      const float4 dv = *(const float4*)&Dv[j2];
      rank += (dv.x < D || (dv.x == D && (j2+0) < j)) ? 1 : 0;
      rank += (dv.y < D || (dv.y == D && (j2+1) < j)) ? 1 : 0;
      rank += (dv.z < D || (dv.z == D && (j2+2) < j)) ? 1 : 0;
      rank += (dv.w < D || (dv.w == D && (j2+3) < j)) ? 1 : 0;
    }
    int K = topk[0];
    if (K<=0 || K>256){
      float f = ((const float*)topk)[0];
      K = (f>=1.f && f<=256.f) ? (int)f : 64;
    }
    const int jb = (b<<8)+j;
    const int sep = abs(idxp[jb] - idxp[bid]);
    const bool m = (rank < K) || (i!=j && sep < KMINC);
    unsigned long long bal = __ballot(m);
    const int l6 = j & 63, wv = j >> 6;
    const int pre = __popcll(bal & ((1ull<<l6)-1ull));
    if (l6==0) wsum[wv] = __popcll(bal);
    __syncthreads();
    int off = 0;
    for (int w2=0;w2<wv;w2++) off += wsum[w2];
    if (m) jlist[bid*96 + off + pre] = j;
    if (j==0) cnt[bid] = wsum[0]+wsum[1]+wsum[2]+wsum[3];
  } else {
    __syncthreads();
  }
}

// ---------------- Kernel C: wave-per-slice gathered pipeline, b128 LDS (r8-verified) ----------------
// grid = 512*SLI/4 (1280), block = 256 = 4 independent waves; wave = one 8-row slice.
// All GEMV LDS reads are 16B (uint4): q-blocked weights (1 b128/iter, conflict-free
// 16B-stride) + 16B broadcast operand rows. Prologue weight copy vectorized uint4.
__global__ __launch_bounds__(256) void k_main(
    const float* __restrict__ pair, const float* __restrict__ xyz,
    const float* __restrict__ g_pair, const float* __restrict__ b_pair,
    const float* __restrict__ be, const float* __restrict__ g_edge,
    const float* __restrict__ b_edge, const float* __restrict__ ba,
    const float* __restrict__ node, const int* __restrict__ cnt,
    const int* __restrict__ jlist, const float* __restrict__ m0bG,
    const unsigned* __restrict__ packW, float* __restrict__ part)
{
  const int tid = threadIdx.x;
  const int w  = tid >> 6;          // wave 0..3
  const int wl = tid & 63;          // lane in wave
  const int r  = (tid >> 5) & 1;    // group in wave
  const int t  = tid & 31;          // lane in group

  __shared__ alignas(16) unsigned WeL[2048];        // 8 KB q-blocked
  __shared__ alignas(16) unsigned WaL[512];         // 2 KB
  __shared__ alignas(16) unsigned W0L[768];         // 3 KB
  __shared__ alignas(16) unsigned WcL[192];         // 768 B
  __shared__ float waD[32];
  __shared__ float beS[32], geS[32], beeS[32], baS[32];
  __shared__ alignas(16) _Float16 pnH[32][128];     // 8 KB
  __shared__ alignas(16) _Float16 edH[32][32];      // 2 KB
  __shared__ alignas(16) _Float16 aH [32][32];      // 2 KB
  __shared__ alignas(16) _Float16 ndH[32][32];      // 2 KB
  __shared__ float cS[32*12];
  __shared__ float xjS[32][9];
  __shared__ float geoS[32][4];

  // ---- vectorized weight copy (uint4) ----
  {
    const uint4* p4 = (const uint4*)packW;
    #pragma unroll
    for (int i2=tid;i2<512;i2+=256) ((uint4*)WeL)[i2] = p4[i2];
    if (tid<128) ((uint4*)WaL)[tid] = p4[512+tid];
    if (tid<192) ((uint4*)W0L)[tid] = p4[640+tid];
    if (tid<48)  ((uint4*)WcL)[tid] = p4[832+tid];
  }
  if (tid<32){
    waD[tid] = ((const float*)packW)[3520+tid];
    beS[tid]=be[tid]; geS[tid]=g_edge[tid]; beeS[tid]=b_edge[tid]; baS[tid]=ba[tid];
  }
  __syncthreads();        // the ONLY block-wide barrier

  const int s    = blockIdx.x*4 + w;   // slice id
  const int item = s / SLI;            // (b,i)
  const int sl   = s - item*SLI;
  const int b    = item >> 8;
  const int n    = cnt[item];
  const int row0 = sl*8;
  const int wrow = w*8;

  float stA = 0.f;
  float ofA = 0.f;

  if (row0 < n){
    const float cax = xyz[(item*3+1)*3+0];
    const float cay = xyz[(item*3+1)*3+1];
    const float caz = xyz[(item*3+1)*3+2];
    bool vals[4];
    // ---- stage 4 rows per group ----
    {
      const float4 gp4 = *(const float4*)&g_pair[4*t];
      const float4 bp4 = *(const float4*)&b_pair[4*t];
      #pragma unroll
      for (int jc=0;jc<4;jc++){
        const int slot = row0 + r*4 + jc;
        vals[jc] = slot < n;
        const int jj = vals[jc] ? jlist[item*96 + slot] : 0;
        const int row = wrow + r*4 + jc;
        const float* prow = &pair[((long)item*256 + jj)*128];
        const float4 pv4 = *(const float4*)&prow[4*t];
        float sm  = wred32(pv4.x+pv4.y+pv4.z+pv4.w);
        float sm2 = wred32(pv4.x*pv4.x+pv4.y*pv4.y+pv4.z*pv4.z+pv4.w*pv4.w);
        float mu = sm*(1.f/128.f);
        float var = sm2*(1.f/128.f)-mu*mu;
        float rs = rsqrtf(var+EPSLN);
        h4 o;
        o[0]=(_Float16)((pv4.x-mu)*rs*gp4.x+bp4.x);
        o[1]=(_Float16)((pv4.y-mu)*rs*gp4.y+bp4.y);
        o[2]=(_Float16)((pv4.z-mu)*rs*gp4.z+bp4.z);
        o[3]=(_Float16)((pv4.w-mu)*rs*gp4.w+bp4.w);
        *(h4*)&pnH[row][4*t] = o;
        const int jb=(b<<8)+jj;
        ndH[row][t] = (_Float16)node[jb*32+t];
        if (t<9) xjS[row][t] = xyz[(size_t)jb*9 + t];
        if (t==0){
          float jx = xyz[(size_t)jb*9+3]-cax;
          float jy = xyz[(size_t)jb*9+4]-cay;
          float jz = xyz[(size_t)jb*9+5]-caz;
          geoS[row][0]=jx; geoS[row][1]=jy; geoS[row][2]=jz;
          geoS[row][3]=sqrtf(jx*jx+jy*jy+jz*jz);
        }
      }
    }
    // ---- edge GEMV (128->32): 16 iters, all-b128 ----
    float ea0[4], ea1[4];
    #pragma unroll
    for (int jc=0;jc<4;jc++){ ea0[jc]=beS[t]; ea1[jc]=0.f; }
    for (int qb=0; qb<16; ++qb){
      const uint4 wv = *(const uint4*)&WeL[qb*128 + t*4];
      #pragma unroll
      for (int jc=0;jc<4;jc++){
        const uint4 pv = *(const uint4*)&pnH[wrow + r*4 + jc][8*qb];
        ea0[jc]=FDOT2(asH2(wv.y), asH2(pv.y), FDOT2(asH2(wv.x), asH2(pv.x), ea0[jc]));
        ea1[jc]=FDOT2(asH2(wv.w), asH2(pv.w), FDOT2(asH2(wv.z), asH2(pv.z), ea1[jc]));
      }
    }
    // ---- edge LN -> edH f16 ----
    #pragma unroll
    for (int jc=0;jc<4;jc++){
      float acc=ea0[jc]+ea1[jc];
      float sm=wred32(acc), sm2=wred32(acc*acc);
      float mu=sm*(1.f/32.f), var=sm2*(1.f/32.f)-mu*mu;
      edH[wrow + r*4 + jc][t] = (_Float16)((acc-mu)*rsqrtf(var+EPSLN)*geS[t]+beeS[t]);
    }
    // ---- a = relu([edge, dist] @ Wa + ba) ----
    float av[4];
    #pragma unroll
    for (int jc=0;jc<4;jc++) av[jc]=baS[t]+geoS[wrow + r*4 + jc][3]*waD[t];
    for (int qb=0; qb<4; ++qb){
      const uint4 wv = *(const uint4*)&WaL[qb*128 + t*4];
      #pragma unroll
      for (int jc=0;jc<4;jc++){
        const uint4 ev = *(const uint4*)&edH[wrow + r*4 + jc][8*qb];
        av[jc]=FDOT2(asH2(wv.w), asH2(ev.w), FDOT2(asH2(wv.z), asH2(ev.z),
                FDOT2(asH2(wv.y), asH2(ev.y), FDOT2(asH2(wv.x), asH2(ev.x), av[jc]))));
      }
    }
    #pragma unroll
    for (int jc=0;jc<4;jc++) aH[wrow + r*4 + jc][t]=(_Float16)fmaxf(av[jc],0.f);
    // ---- m0: a-part lanes t<16 (W0 blocks 0..3), node-part t>=16 (blocks 8..11) ----
    {
      const int half = t>>4, tc = t&15;
      const int wb = half ? 8 : 0;
      const float m0b = half ? 0.f : m0bG[item*16+tc];
      float m0v[4];
      #pragma unroll
      for (int jc=0;jc<4;jc++) m0v[jc]=m0b;
      for (int qb=0;qb<4;++qb){
        const uint4 wv = *(const uint4*)&W0L[(wb+qb)*64 + tc*4];
        #pragma unroll
        for (int jc=0;jc<4;jc++){
          const _Float16* opb = half ? &ndH[wrow + r*4 + jc][0] : &aH[wrow + r*4 + jc][0];
          const uint4 ov = *(const uint4*)&opb[8*qb];
          m0v[jc]=FDOT2(asH2(wv.w), asH2(ov.w), FDOT2(asH2(wv.z), asH2(ov.z),
                   FDOT2(asH2(wv.y), asH2(ov.y), FDOT2(asH2(wv.x), asH2(ov.x), m0v[jc]))));
        }
      }
      #pragma unroll
      for (int jc=0;jc<4;jc++){
        float tot = m0v[jc] + __shfl_xor(m0v[jc], 16);
        if (t<16 && vals[jc]) stA += fmaxf(tot, 0.f);
      }
    }
    // ---- c1/c2 from a: lanes t<12 k-rows 0..15 (blocks 0..1), lanes 12..23 k 16..31 (blocks 2..3) ----
    {
      const bool up = (t>=12 && t<24);
      const int tc12 = up ? t-12 : (t<12 ? t : 0);
      const int wb = up ? 2 : 0;
      const int koff = up ? 16 : 0;
      float cv[4]={0.f,0.f,0.f,0.f};
      for (int qb=0;qb<2;++qb){
        const uint4 wv = *(const uint4*)&WcL[(wb+qb)*48 + tc12*4];
        #pragma unroll
        for (int jc=0;jc<4;jc++){
          const uint4 av2 = *(const uint4*)&aH[wrow + r*4 + jc][koff + 8*qb];
          cv[jc]=FDOT2(asH2(wv.w), asH2(av2.w), FDOT2(asH2(wv.z), asH2(av2.z),
                  FDOT2(asH2(wv.y), asH2(av2.y), FDOT2(asH2(wv.x), asH2(av2.x), cv[jc]))));
        }
      }
      #pragma unroll
      for (int jc=0;jc<4;jc++){
        const int src = (t<12) ? t+12 : (up ? t-12 : t);
        float other = __shfl(cv[jc], src, 32);
        if (t<12) cS[(wrow + r*4 + jc)*12+t] = cv[jc]+other;
      }
    }
    // ---- offset accumulation (t<9) ----
    if (t<9){
      const int o=t/3, x=t-o*3;
      #pragma unroll
      for (int jc=0;jc<4;jc++){
        if (!vals[jc]) continue;
        const int row = wrow + r*4 + jc;
        const float dj = geoS[row][3];
        const float dh = geoS[row][x]/(dj+1e-8f);
        const float* cr = &cS[row*12];
        float val = cr[o]*dh;
        const float caxj = xjS[row][3+x];
        #pragma unroll
        for (int c=0;c<3;c++){
          val += cr[3+o*3+c]*(xjS[row][c*3+x]-caxj);
        }
        ofA += val;
      }
    }
  }

  stA += __shfl_xor(stA, 32);
  ofA += __shfl_xor(ofA, 32);
  if (wl < 16) part[s*28 + wl] = stA;
  if (wl < 9)  part[s*28 + 16 + wl] = ofA;
}

// ---------------- Kernel F: combine partials, scale by deg, form xyz_new ----------------
// grid = B*L (512), block = 64
__global__ __launch_bounds__(64) void k_fin(
    const float* __restrict__ xyz, const int* __restrict__ cnt,
    const float* __restrict__ part, float* __restrict__ out)
{
  const int bid = blockIdx.x;
  const int t = threadIdx.x;
  __shared__ float offF[9];
  const int n = cnt[bid];
  const float invd = 1.f/fmaxf((float)n,1.f);
  if (t<16){
    float s=0.f;
    #pragma unroll
    for (int k2=0;k2<SLI;k2++) s += part[(bid*SLI+k2)*28 + t];
    out[4608 + bid*16 + t] = s*invd;           // state
  } else if (t<25){
    float s=0.f;
    #pragma unroll
    for (int k2=0;k2<SLI;k2++) s += part[(bid*SLI+k2)*28 + t];
    offF[t-16] = s*invd;
  }
  __syncthreads();
  if (t<9){
    const int o=t/3, x=t-o*3;
    const float cac = xyz[(bid*3+1)*3+x];
    const float CA = cac + offF[3+x];          // offset[:,:,1]
    const float v = (o==1)? CA : (CA + offF[o*3+x]);
    out[bid*9 + t] = v;                        // xyz_new
  }
}

extern "C" void kernel_launch(void* const* d_in, const int* in_sizes, int n_in,
                              void* d_out, int out_size, void* d_ws, size_t ws_size,
                              hipStream_t stream)
{
  const float* msa     = (const float*)d_in[0];
  const float* pair    = (const float*)d_in[1];
  const float* xyz     = (const float*)d_in[2];
  const float* seq1hot = (const float*)d_in[3];
  const float* g_msa   = (const float*)d_in[4];
  const float* b_msa   = (const float*)d_in[5];
  const float* g_pair  = (const float*)d_in[6];
  const float* b_pair  = (const float*)d_in[7];
  const float* Wq      = (const float*)d_in[8];
  const float* bq      = (const float*)d_in[9];
  const float* Wk      = (const float*)d_in[10];
  const float* bk      = (const float*)d_in[11];
  const float* Wx      = (const float*)d_in[12];
  const float* bx      = (const float*)d_in[13];
  const float* g_node  = (const float*)d_in[14];
  const float* b_node  = (const float*)d_in[15];
  const float* We      = (const float*)d_in[16];
  const float* be      = (const float*)d_in[17];
  const float* g_edge  = (const float*)d_in[18];
  const float* b_edge  = (const float*)d_in[19];
  const float* Wa      = (const float*)d_in[20];
  const float* ba      = (const float*)d_in[21];
  const float* W0      = (const float*)d_in[22];
  const float* b0      = (const float*)d_in[23];
  const float* Wc1     = (const float*)d_in[24];
  const float* Wc2     = (const float*)d_in[25];
  const int*   idx     = (const int*)d_in[26];
  const int*   topk    = (const int*)d_in[27];
  float* out = (float*)d_out;

  float* wsf = (float*)d_ws;
  float*    node  = wsf + WS_NODE;
  int*      cnt   = (int*)(wsf + WS_CNT);
  int*      jlist = (int*)(wsf + WS_JLIST);
  float*    m0bG  = wsf + WS_M0B;
  float*    partb = wsf + WS_PART;
  unsigned* packW = (unsigned*)(wsf + WS_PACKW);

  k_prep<<<512, 512, 0, stream>>>(msa, seq1hot, xyz, idx, topk, g_msa, b_msa,
                                  Wq, bq, Wk, bk, Wx, bx, g_node, b_node,
                                  We, Wa, W0, b0, Wc1, Wc2,
                                  node, cnt, jlist, m0bG, packW);
  k_main<<<512*SLI/4, 256, 0, stream>>>(pair, xyz, g_pair, b_pair, be, g_edge,
                                        b_edge, ba, node, cnt, jlist, m0bG,
                                        packW, partb);
  k_fin<<<512, 64, 0, stream>>>(xyz, cnt, partb, out);
}

// Round 17
// 43.786 us; speedup vs baseline: 1.5372x; 1.0575x over previous
//
#include <hip/hip_runtime.h>

#define EPSLN 1e-5f
#define KMINC 9
#define SLI   10         // slices per (b,i), 8 rows each -> covers n <= 80

typedef _Float16 h2 __attribute__((ext_vector_type(2)));
typedef _Float16 h4 __attribute__((ext_vector_type(4)));

#if defined(__has_builtin)
#if __has_builtin(__builtin_amdgcn_fdot2)
#define FDOT2(a,b,c) __builtin_amdgcn_fdot2((a),(b),(c),false)
#endif
#endif
#ifndef FDOT2
#define FDOT2(a,b,c) ((c) + (float)(a)[0]*(float)(b)[0] + (float)(a)[1]*(float)(b)[1])
#endif

__device__ __forceinline__ h2 mk2(float a, float b){
  h2 v; v[0]=(_Float16)a; v[1]=(_Float16)b; return v;
}
__device__ __forceinline__ unsigned h2bits(h2 v){
  union { h2 h; unsigned u; } c; c.h = v; return c.u;
}
__device__ __forceinline__ h2 asH2(unsigned u){
  union { unsigned u; h2 h; } c; c.u = u; return c.h;
}

// ---- DPP-based reductions: butterflies on the VALU pipe, not LDS (ds_bpermute) ----
// ctrl must be a compile-time constant -> template parameter.
// 16-lane sum-to-all: quad_perm xor1 (0x0B1), quad_perm xor2 (0x04E),
// row_ror:4 (0x124), row_ror:8 (0x128). Cross-row steps keep 1-2 shfl (ds) ops.
template<int CTRL>
__device__ __forceinline__ float dppadd(float v){
  union { float f; int i; } a, r;
  a.f = v;
  r.i = __builtin_amdgcn_update_dpp(a.i, a.i, CTRL, 0xf, 0xf, true);
  return v + r.f;
}
__device__ __forceinline__ float wred16d(float v){
  v = dppadd<0x0B1>(v);
  v = dppadd<0x04E>(v);
  v = dppadd<0x124>(v);
  v = dppadd<0x128>(v);
  return v;
}
__device__ __forceinline__ float wred32(float v){
  v = wred16d(v);
  return v + __shfl_xor(v, 16, 64);
}
__device__ __forceinline__ float wred64(float v){
  v = wred16d(v);
  v += __shfl_xor(v, 16, 64);
  return v + __shfl_xor(v, 32, 64);
}

// ws word-offsets
#define WS_NODE   0
#define WS_CNT    16384
#define WS_JLIST  16896       // 512*96 ints
#define WS_M0B    66048       // 512*16 f32
#define WS_PART   74240       // 512*SLI*28 f32 = 143360
#define WS_PACKW  217600      // q-blocked packed weights (3552 u32)

// ---------------- Kernel P: msa-LN/attention/node + m0b + top-k mask + weight packing ----------------
// grid = B*L (512), block = 512 (8 waves)
__global__ __launch_bounds__(512) void k_prep(
    const float* __restrict__ msa, const float* __restrict__ seq1hot,
    const float* __restrict__ xyz, const int* __restrict__ idxp,
    const int* __restrict__ topk,
    const float* __restrict__ g_msa, const float* __restrict__ b_msa,
    const float* __restrict__ Wq, const float* __restrict__ bq,
    const float* __restrict__ Wk, const float* __restrict__ bk,
    const float* __restrict__ Wx, const float* __restrict__ bx,
    const float* __restrict__ g_node, const float* __restrict__ b_node,
    const float* __restrict__ We, const float* __restrict__ Wa,
    const float* __restrict__ W0, const float* __restrict__ b0,
    const float* __restrict__ Wc1, const float* __restrict__ Wc2,
    float* __restrict__ node, int* __restrict__ cnt, int* __restrict__ jlist,
    float* __restrict__ m0bG, unsigned* __restrict__ packW)
{
  const int bid = blockIdx.x;          // b*256 + l  (l == i)
  const int b = bid >> 8;
  const int tid = threadIdx.x;
  const int w = tid >> 6, lane = tid & 63;   // 8 waves

  __shared__ float mn[32][64];
  __shared__ float qS[64];
  __shared__ float scS[32];
  __shared__ float redS[8][64];
  __shared__ float ssumS[8];
  __shared__ float nodeS[32];
  __shared__ alignas(16) float Dv[256];
  __shared__ int   wsum[4];

  // ---- block 0 packs weights q-blocked f16 into ws (for k_main) ----
  if (bid==0){
    for (int i=tid;i<2048;i+=512){
      int qb=i>>7, r7=i&127, t=r7>>2, i2=r7&3, q=4*qb+i2;
      packW[i] = h2bits(mk2(We[(2*q)*32+t], We[(2*q+1)*32+t]));
    }
    for (int i=tid;i<512; i+=512){
      int qb=i>>7, r7=i&127, t=r7>>2, i2=r7&3, q=4*qb+i2;
      packW[2048+i] = h2bits(mk2(Wa[(2*q)*32+t], Wa[(2*q+1)*32+t]));
    }
    for (int i=tid;i<768; i+=512){
      int qb=i>>6, r6=i&63, tc=r6>>2, i2=r6&3, q=4*qb+i2;
      packW[2560+i] = h2bits(mk2(W0[(2*q)*16+tc], W0[(2*q+1)*16+tc]));
    }
    if (tid<192){
      int qb=tid/48, r48=tid%48, tc=r48>>2, i2=r48&3, q=4*qb+i2;
      float lo = (tc<3)? Wc1[(2*q)*3+tc]   : Wc2[(2*q)*9+(tc-3)];
      float hi = (tc<3)? Wc1[(2*q+1)*3+tc] : Wc2[(2*q+1)*9+(tc-3)];
      packW[3328+tid] = h2bits(mk2(lo,hi));
    }
    if (tid<32) ((float*)packW)[3520+tid] = Wa[32*32+tid];
  }

  // ---- msa LN: wave w rows w, w+8, w+16, w+24 ----
  const float gm = g_msa[lane], bm = b_msa[lane];
  for (int nn=w; nn<32; nn+=8){
    float x = msa[(size_t)(((b*32+nn)<<8)+(bid&255))*64 + lane];
    float s = wred64(x), s2 = wred64(x*x);
    float mu = s*(1.f/64.f);
    float var = s2*(1.f/64.f) - mu*mu;
    mn[nn][lane] = (x-mu)*rsqrtf(var+EPSLN)*gm + bm;
  }
  __syncthreads();
  // ---- q[e=lane]: partial over d-range per wave ----
  {
    float p = (w==0)? bq[lane] : 0.f;
    for (int d=w*8; d<w*8+8; d++) p += mn[0][d]*Wq[d*64+lane];
    redS[w][lane] = p;
  }
  __syncthreads();
  if (w==0){
    float q = 0.f;
    #pragma unroll
    for (int k=0;k<8;k++) q += redS[k][lane];
    qS[lane] = q*0.125f;               // 1/sqrt(64)
  }
  __syncthreads();
  // ---- qk[d=lane]: partial over e-range per wave ----
  {
    float p = 0.f;
    for (int e=w*8; e<w*8+8; e++) p += Wk[lane*64+e]*qS[e];
    redS[w][lane] = p;
  }
  __syncthreads();
  float qk = 0.f;
  #pragma unroll
  for (int k=0;k<8;k++) qk += redS[k][lane];
  const float qb_ = wred64(qS[lane]*bk[lane]);
  // ---- scores: wave w rows w*4..w*4+3 ----
  for (int nn=w*4; nn<w*4+4; nn++){
    float p = wred64(mn[nn][lane]*qk);
    if (lane==0) scS[nn] = p + qb_;
  }
  __syncthreads();
  // ---- softmax + weighted msa ----
  float mx = -1e30f;
  for (int nn=0; nn<32; nn++) mx = fmaxf(mx, scS[nn]);
  float ps=0.f, pm=0.f;
  for (int nn=w*4; nn<w*4+4; nn++){
    float e = expf(scS[nn]-mx);
    ps += e; pm += e*mn[nn][lane];
  }
  redS[w][lane] = pm;
  if (lane==0) ssumS[w] = ps;
  __syncthreads();
  if (w==0){
    float ssum = 0.f, acc = 0.f;
    #pragma unroll
    for (int k=0;k<8;k++){ ssum += ssumS[k]; acc += redS[k][lane]; }
    qS[lane] = acc / ssum;
  }
  __syncthreads();
  if (tid<32){
    float acc = bx[tid];
    for (int k=0;k<64;k++) acc += qS[k]*Wx[k*32+tid];
    const float* s1 = &seq1hot[bid*21];
    for (int k=0;k<21;k++) acc += s1[k]*Wx[(64+k)*32+tid];
    float s = wred32(acc), s2 = wred32(acc*acc);
    float mu = s*(1.f/32.f), var = s2*(1.f/32.f)-mu*mu;
    float v = (acc-mu)*rsqrtf(var+EPSLN)*g_node[tid] + b_node[tid];
    node[bid*32+tid] = v;
    nodeS[tid] = v;
  }
  __syncthreads();
  if (tid<16){
    float acc = b0[tid];
    for (int k=0;k<32;k++) acc += nodeS[k]*W0[(32+k)*16+tid];
    m0bG[bid*16+tid] = acc;
  }

  // --- Phase 2: distances, exact stable top-k rank, compaction (tid<256, thread=j) ---
  const bool act = tid < 256;
  const int i = bid & 255;
  const int j = tid;
  float D = 0.f;
  if (act){
    const float cax = xyz[(bid*3+1)*3+0];
    const float cay = xyz[(bid*3+1)*3+1];
    const float caz = xyz[(bid*3+1)*3+2];
    const int jb = (b<<8)+j;
    float dx = xyz[(jb*3+1)*3+0]-cax;
    float dy = xyz[(jb*3+1)*3+1]-cay;
    float dz = xyz[(jb*3+1)*3+2]-caz;
    D = sqrtf(dx*dx+dy*dy+dz*dz) + (i==j ? 999.9f : 0.f);
  }
  __syncthreads();
  if (act) Dv[j] = D;
  __syncthreads();
  if (act){
    int rank = 0;
    for (int j2=0;j2<256;j2+=4){
      const float4 dv = *(const float4*)&Dv[j2];
      rank += (dv.x < D || (dv.x == D && (j2+0) < j)) ? 1 : 0;
      rank += (dv.y < D || (dv.y == D && (j2+1) < j)) ? 1 : 0;
      rank += (dv.z < D || (dv.z == D && (j2+2) < j)) ? 1 : 0;
      rank += (dv.w < D || (dv.w == D && (j2+3) < j)) ? 1 : 0;
    }
    int K = topk[0];
    if (K<=0 || K>256){
      float f = ((const float*)topk)[0];
      K = (f>=1.f && f<=256.f) ? (int)f : 64;
    }
    const int jb = (b<<8)+j;
    const int sep = abs(idxp[jb] - idxp[bid]);
    const bool m = (rank < K) || (i!=j && sep < KMINC);
    unsigned long long bal = __ballot(m);
    const int l6 = j & 63, wv = j >> 6;
    const int pre = __popcll(bal & ((1ull<<l6)-1ull));
    if (l6==0) wsum[wv] = __popcll(bal);
    __syncthreads();
    int off = 0;
    for (int w2=0;w2<wv;w2++) off += wsum[w2];
    if (m) jlist[bid*96 + off + pre] = j;
    if (j==0) cnt[bid] = wsum[0]+wsum[1]+wsum[2]+wsum[3];
  } else {
    __syncthreads();
  }
}

// ---------------- Kernel C: wave-per-slice gathered pipeline, b128 LDS (r8/r15-verified) ----------------
// grid = 512*SLI/4 (1280), block = 256 = 4 independent waves; wave = one 8-row slice.
// All GEMV LDS reads are 16B (uint4); LN reductions now DPP-based (VALU pipe).
__global__ __launch_bounds__(256) void k_main(
    const float* __restrict__ pair, const float* __restrict__ xyz,
    const float* __restrict__ g_pair, const float* __restrict__ b_pair,
    const float* __restrict__ be, const float* __restrict__ g_edge,
    const float* __restrict__ b_edge, const float* __restrict__ ba,
    const float* __restrict__ node, const int* __restrict__ cnt,
    const int* __restrict__ jlist, const float* __restrict__ m0bG,
    const unsigned* __restrict__ packW, float* __restrict__ part)
{
  const int tid = threadIdx.x;
  const int w  = tid >> 6;          // wave 0..3
  const int wl = tid & 63;          // lane in wave
  const int r  = (tid >> 5) & 1;    // group in wave
  const int t  = tid & 31;          // lane in group

  __shared__ alignas(16) unsigned WeL[2048];        // 8 KB q-blocked
  __shared__ alignas(16) unsigned WaL[512];         // 2 KB
  __shared__ alignas(16) unsigned W0L[768];         // 3 KB
  __shared__ alignas(16) unsigned WcL[192];         // 768 B
  __shared__ float waD[32];
  __shared__ float beS[32], geS[32], beeS[32], baS[32];
  __shared__ alignas(16) _Float16 pnH[32][128];     // 8 KB
  __shared__ alignas(16) _Float16 edH[32][32];      // 2 KB
  __shared__ alignas(16) _Float16 aH [32][32];      // 2 KB
  __shared__ alignas(16) _Float16 ndH[32][32];      // 2 KB
  __shared__ float cS[32*12];
  __shared__ float xjS[32][9];
  __shared__ float geoS[32][4];

  // ---- vectorized weight copy (uint4) ----
  {
    const uint4* p4 = (const uint4*)packW;
    #pragma unroll
    for (int i2=tid;i2<512;i2+=256) ((uint4*)WeL)[i2] = p4[i2];
    if (tid<128) ((uint4*)WaL)[tid] = p4[512+tid];
    if (tid<192) ((uint4*)W0L)[tid] = p4[640+tid];
    if (tid<48)  ((uint4*)WcL)[tid] = p4[832+tid];
  }
  if (tid<32){
    waD[tid] = ((const float*)packW)[3520+tid];
    beS[tid]=be[tid]; geS[tid]=g_edge[tid]; beeS[tid]=b_edge[tid]; baS[tid]=ba[tid];
  }
  __syncthreads();        // the ONLY block-wide barrier

  const int s    = blockIdx.x*4 + w;   // slice id
  const int item = s / SLI;            // (b,i)
  const int sl   = s - item*SLI;
  const int b    = item >> 8;
  const int n    = cnt[item];
  const int row0 = sl*8;
  const int wrow = w*8;

  float stA = 0.f;
  float ofA = 0.f;

  if (row0 < n){
    const float cax = xyz[(item*3+1)*3+0];
    const float cay = xyz[(item*3+1)*3+1];
    const float caz = xyz[(item*3+1)*3+2];
    bool vals[4];
    // ---- stage 4 rows per group ----
    {
      const float4 gp4 = *(const float4*)&g_pair[4*t];
      const float4 bp4 = *(const float4*)&b_pair[4*t];
      #pragma unroll
      for (int jc=0;jc<4;jc++){
        const int slot = row0 + r*4 + jc;
        vals[jc] = slot < n;
        const int jj = vals[jc] ? jlist[item*96 + slot] : 0;
        const int row = wrow + r*4 + jc;
        const float* prow = &pair[((long)item*256 + jj)*128];
        const float4 pv4 = *(const float4*)&prow[4*t];
        float sm  = wred32(pv4.x+pv4.y+pv4.z+pv4.w);
        float sm2 = wred32(pv4.x*pv4.x+pv4.y*pv4.y+pv4.z*pv4.z+pv4.w*pv4.w);
        float mu = sm*(1.f/128.f);
        float var = sm2*(1.f/128.f)-mu*mu;
        float rs = rsqrtf(var+EPSLN);
        h4 o;
        o[0]=(_Float16)((pv4.x-mu)*rs*gp4.x+bp4.x);
        o[1]=(_Float16)((pv4.y-mu)*rs*gp4.y+bp4.y);
        o[2]=(_Float16)((pv4.z-mu)*rs*gp4.z+bp4.z);
        o[3]=(_Float16)((pv4.w-mu)*rs*gp4.w+bp4.w);
        *(h4*)&pnH[row][4*t] = o;
        const int jb=(b<<8)+jj;
        ndH[row][t] = (_Float16)node[jb*32+t];
        if (t<9) xjS[row][t] = xyz[(size_t)jb*9 + t];
        if (t==0){
          float jx = xyz[(size_t)jb*9+3]-cax;
          float jy = xyz[(size_t)jb*9+4]-cay;
          float jz = xyz[(size_t)jb*9+5]-caz;
          geoS[row][0]=jx; geoS[row][1]=jy; geoS[row][2]=jz;
          geoS[row][3]=sqrtf(jx*jx+jy*jy+jz*jz);
        }
      }
    }
    // ---- edge GEMV (128->32): 16 iters, all-b128 ----
    float ea0[4], ea1[4];
    #pragma unroll
    for (int jc=0;jc<4;jc++){ ea0[jc]=beS[t]; ea1[jc]=0.f; }
    for (int qb=0; qb<16; ++qb){
      const uint4 wv = *(const uint4*)&WeL[qb*128 + t*4];
      #pragma unroll
      for (int jc=0;jc<4;jc++){
        const uint4 pv = *(const uint4*)&pnH[wrow + r*4 + jc][8*qb];
        ea0[jc]=FDOT2(asH2(wv.y), asH2(pv.y), FDOT2(asH2(wv.x), asH2(pv.x), ea0[jc]));
        ea1[jc]=FDOT2(asH2(wv.w), asH2(pv.w), FDOT2(asH2(wv.z), asH2(pv.z), ea1[jc]));
      }
    }
    // ---- edge LN -> edH f16 ----
    #pragma unroll
    for (int jc=0;jc<4;jc++){
      float acc=ea0[jc]+ea1[jc];
      float sm=wred32(acc), sm2=wred32(acc*acc);
      float mu=sm*(1.f/32.f), var=sm2*(1.f/32.f)-mu*mu;
      edH[wrow + r*4 + jc][t] = (_Float16)((acc-mu)*rsqrtf(var+EPSLN)*geS[t]+beeS[t]);
    }
    // ---- a = relu([edge, dist] @ Wa + ba) ----
    float av[4];
    #pragma unroll
    for (int jc=0;jc<4;jc++) av[jc]=baS[t]+geoS[wrow + r*4 + jc][3]*waD[t];
    for (int qb=0; qb<4; ++qb){
      const uint4 wv = *(const uint4*)&WaL[qb*128 + t*4];
      #pragma unroll
      for (int jc=0;jc<4;jc++){
        const uint4 ev = *(const uint4*)&edH[wrow + r*4 + jc][8*qb];
        av[jc]=FDOT2(asH2(wv.w), asH2(ev.w), FDOT2(asH2(wv.z), asH2(ev.z),
                FDOT2(asH2(wv.y), asH2(ev.y), FDOT2(asH2(wv.x), asH2(ev.x), av[jc]))));
      }
    }
    #pragma unroll
    for (int jc=0;jc<4;jc++) aH[wrow + r*4 + jc][t]=(_Float16)fmaxf(av[jc],0.f);
    // ---- m0: a-part lanes t<16 (W0 blocks 0..3), node-part t>=16 (blocks 8..11) ----
    {
      const int half = t>>4, tc = t&15;
      const int wb = half ? 8 : 0;
      const float m0b = half ? 0.f : m0bG[item*16+tc];
      float m0v[4];
      #pragma unroll
      for (int jc=0;jc<4;jc++) m0v[jc]=m0b;
      for (int qb=0;qb<4;++qb){
        const uint4 wv = *(const uint4*)&W0L[(wb+qb)*64 + tc*4];
        #pragma unroll
        for (int jc=0;jc<4;jc++){
          const _Float16* opb = half ? &ndH[wrow + r*4 + jc][0] : &aH[wrow + r*4 + jc][0];
          const uint4 ov = *(const uint4*)&opb[8*qb];
          m0v[jc]=FDOT2(asH2(wv.w), asH2(ov.w), FDOT2(asH2(wv.z), asH2(ov.z),
                   FDOT2(asH2(wv.y), asH2(ov.y), FDOT2(asH2(wv.x), asH2(ov.x), m0v[jc]))));
        }
      }
      #pragma unroll
      for (int jc=0;jc<4;jc++){
        float tot = m0v[jc] + __shfl_xor(m0v[jc], 16);
        if (t<16 && vals[jc]) stA += fmaxf(tot, 0.f);
      }
    }
    // ---- c1/c2 from a: lanes t<12 k-rows 0..15 (blocks 0..1), lanes 12..23 k 16..31 (blocks 2..3) ----
    {
      const bool up = (t>=12 && t<24);
      const int tc12 = up ? t-12 : (t<12 ? t : 0);
      const int wb = up ? 2 : 0;
      const int koff = up ? 16 : 0;
      float cv[4]={0.f,0.f,0.f,0.f};
      for (int qb=0;qb<2;++qb){
        const uint4 wv = *(const uint4*)&WcL[(wb+qb)*48 + tc12*4];
        #pragma unroll
        for (int jc=0;jc<4;jc++){
          const uint4 av2 = *(const uint4*)&aH[wrow + r*4 + jc][koff + 8*qb];
          cv[jc]=FDOT2(asH2(wv.w), asH2(av2.w), FDOT2(asH2(wv.z), asH2(av2.z),
                  FDOT2(asH2(wv.y), asH2(av2.y), FDOT2(asH2(wv.x), asH2(av2.x), cv[jc]))));
        }
      }
      #pragma unroll
      for (int jc=0;jc<4;jc++){
        const int src = (t<12) ? t+12 : (up ? t-12 : t);
        float other = __shfl(cv[jc], src, 32);
        if (t<12) cS[(wrow + r*4 + jc)*12+t] = cv[jc]+other;
      }
    }
    // ---- offset accumulation (t<9) ----
    if (t<9){
      const int o=t/3, x=t-o*3;
      #pragma unroll
      for (int jc=0;jc<4;jc++){
        if (!vals[jc]) continue;
        const int row = wrow + r*4 + jc;
        const float dj = geoS[row][3];
        const float dh = geoS[row][x]/(dj+1e-8f);
        const float* cr = &cS[row*12];
        float val = cr[o]*dh;
        const float caxj = xjS[row][3+x];
        #pragma unroll
        for (int c=0;c<3;c++){
          val += cr[3+o*3+c]*(xjS[row][c*3+x]-caxj);
        }
        ofA += val;
      }
    }
  }

  stA += __shfl_xor(stA, 32);
  ofA += __shfl_xor(ofA, 32);
  if (wl < 16) part[s*28 + wl] = stA;
  if (wl < 9)  part[s*28 + 16 + wl] = ofA;
}

// ---------------- Kernel F: combine partials, scale by deg, form xyz_new ----------------
// grid = B*L (512), block = 64
__global__ __launch_bounds__(64) void k_fin(
    const float* __restrict__ xyz, const int* __restrict__ cnt,
    const float* __restrict__ part, float* __restrict__ out)
{
  const int bid = blockIdx.x;
  const int t = threadIdx.x;
  __shared__ float offF[9];
  const int n = cnt[bid];
  const float invd = 1.f/fmaxf((float)n,1.f);
  if (t<16){
    float s=0.f;
    #pragma unroll
    for (int k2=0;k2<SLI;k2++) s += part[(bid*SLI+k2)*28 + t];
    out[4608 + bid*16 + t] = s*invd;           // state
  } else if (t<25){
    float s=0.f;
    #pragma unroll
    for (int k2=0;k2<SLI;k2++) s += part[(bid*SLI+k2)*28 + t];
    offF[t-16] = s*invd;
  }
  __syncthreads();
  if (t<9){
    const int o=t/3, x=t-o*3;
    const float cac = xyz[(bid*3+1)*3+x];
    const float CA = cac + offF[3+x];          // offset[:,:,1]
    const float v = (o==1)? CA : (CA + offF[o*3+x]);
    out[bid*9 + t] = v;                        // xyz_new
  }
}

extern "C" void kernel_launch(void* const* d_in, const int* in_sizes, int n_in,
                              void* d_out, int out_size, void* d_ws, size_t ws_size,
                              hipStream_t stream)
{
  const float* msa     = (const float*)d_in[0];
  const float* pair    = (const float*)d_in[1];
  const float* xyz     = (const float*)d_in[2];
  const float* seq1hot = (const float*)d_in[3];
  const float* g_msa   = (const float*)d_in[4];
  const float* b_msa   = (const float*)d_in[5];
  const float* g_pair  = (const float*)d_in[6];
  const float* b_pair  = (const float*)d_in[7];
  const float* Wq      = (const float*)d_in[8];
  const float* bq      = (const float*)d_in[9];
  const float* Wk      = (const float*)d_in[10];
  const float* bk      = (const float*)d_in[11];
  const float* Wx      = (const float*)d_in[12];
  const float* bx      = (const float*)d_in[13];
  const float* g_node  = (const float*)d_in[14];
  const float* b_node  = (const float*)d_in[15];
  const float* We      = (const float*)d_in[16];
  const float* be      = (const float*)d_in[17];
  const float* g_edge  = (const float*)d_in[18];
  const float* b_edge  = (const float*)d_in[19];
  const float* Wa      = (const float*)d_in[20];
  const float* ba      = (const float*)d_in[21];
  const float* W0      = (const float*)d_in[22];
  const float* b0      = (const float*)d_in[23];
  const float* Wc1     = (const float*)d_in[24];
  const float* Wc2     = (const float*)d_in[25];
  const int*   idx     = (const int*)d_in[26];
  const int*   topk    = (const int*)d_in[27];
  float* out = (float*)d_out;

  float* wsf = (float*)d_ws;
  float*    node  = wsf + WS_NODE;
  int*      cnt   = (int*)(wsf + WS_CNT);
  int*      jlist = (int*)(wsf + WS_JLIST);
  float*    m0bG  = wsf + WS_M0B;
  float*    partb = wsf + WS_PART;
  unsigned* packW = (unsigned*)(wsf + WS_PACKW);

  k_prep<<<512, 512, 0, stream>>>(msa, seq1hot, xyz, idx, topk, g_msa, b_msa,
                                  Wq, bq, Wk, bk, Wx, bx, g_node, b_node,
                                  We, Wa, W0, b0, Wc1, Wc2,
                                  node, cnt, jlist, m0bG, packW);
  k_main<<<512*SLI/4, 256, 0, stream>>>(pair, xyz, g_pair, b_pair, be, g_edge,
                                        b_edge, ba, node, cnt, jlist, m0bG,
                                        packW, partb);
  k_fin<<<512, 64, 0, stream>>>(xyz, cnt, partb, out);
}

// Round 18
// 39.426 us; speedup vs baseline: 1.7073x; 1.1106x over previous
//
#include <hip/hip_runtime.h>

#define EPSLN 1e-5f
#define KMINC 9
#define SLI   10         // slices per (b,i), 8 rows each -> covers n <= 80

typedef _Float16 h2 __attribute__((ext_vector_type(2)));
typedef _Float16 h4 __attribute__((ext_vector_type(4)));

#if defined(__has_builtin)
#if __has_builtin(__builtin_amdgcn_fdot2)
#define FDOT2(a,b,c) __builtin_amdgcn_fdot2((a),(b),(c),false)
#endif
#endif
#ifndef FDOT2
#define FDOT2(a,b,c) ((c) + (float)(a)[0]*(float)(b)[0] + (float)(a)[1]*(float)(b)[1])
#endif

__device__ __forceinline__ h2 mk2(float a, float b){
  h2 v; v[0]=(_Float16)a; v[1]=(_Float16)b; return v;
}
__device__ __forceinline__ unsigned h2bits(h2 v){
  union { h2 h; unsigned u; } c; c.h = v; return c.u;
}
__device__ __forceinline__ h2 asH2(unsigned u){
  union { unsigned u; h2 h; } c; c.u = u; return c.h;
}

// ---- DPP-based reductions (r17-verified): butterflies on the VALU pipe ----
template<int CTRL>
__device__ __forceinline__ float dppadd(float v){
  union { float f; int i; } a, r;
  a.f = v;
  r.i = __builtin_amdgcn_update_dpp(a.i, a.i, CTRL, 0xf, 0xf, true);
  return v + r.f;
}
__device__ __forceinline__ float wred16d(float v){
  v = dppadd<0x0B1>(v);
  v = dppadd<0x04E>(v);
  v = dppadd<0x124>(v);
  v = dppadd<0x128>(v);
  return v;
}
__device__ __forceinline__ float wred32(float v){
  v = wred16d(v);
  return v + __shfl_xor(v, 16, 64);
}
__device__ __forceinline__ float wred64(float v){
  v = wred16d(v);
  v += __shfl_xor(v, 16, 64);
  return v + __shfl_xor(v, 32, 64);
}

// ws word-offsets
#define WS_NODE   0
#define WS_CNT    16384
#define WS_JLIST  16896       // 512*96 ints
#define WS_M0B    66048       // 512*16 f32
#define WS_PART   74240       // 512*SLI*28 f32 = 143360
#define WS_PACKW  217600      // q-blocked packed weights (3552 u32)

// ---------------- Kernel P: msa-LN/attention/node + m0b + top-k mask + weight packing ----------------
// grid = B*L (512), block = 512 (8 waves). Phase-2 rank scan split across BOTH thread
// halves (r18: threads 256-511 were idle; now each half scans 128 of 256 Dv entries).
__global__ __launch_bounds__(512) void k_prep(
    const float* __restrict__ msa, const float* __restrict__ seq1hot,
    const float* __restrict__ xyz, const int* __restrict__ idxp,
    const int* __restrict__ topk,
    const float* __restrict__ g_msa, const float* __restrict__ b_msa,
    const float* __restrict__ Wq, const float* __restrict__ bq,
    const float* __restrict__ Wk, const float* __restrict__ bk,
    const float* __restrict__ Wx, const float* __restrict__ bx,
    const float* __restrict__ g_node, const float* __restrict__ b_node,
    const float* __restrict__ We, const float* __restrict__ Wa,
    const float* __restrict__ W0, const float* __restrict__ b0,
    const float* __restrict__ Wc1, const float* __restrict__ Wc2,
    float* __restrict__ node, int* __restrict__ cnt, int* __restrict__ jlist,
    float* __restrict__ m0bG, unsigned* __restrict__ packW)
{
  const int bid = blockIdx.x;          // b*256 + l  (l == i)
  const int b = bid >> 8;
  const int tid = threadIdx.x;
  const int w = tid >> 6, lane = tid & 63;   // 8 waves

  __shared__ float mn[32][64];
  __shared__ float qS[64];
  __shared__ float scS[32];
  __shared__ float redS[8][64];
  __shared__ float ssumS[8];
  __shared__ float nodeS[32];
  __shared__ alignas(16) float Dv[256];
  __shared__ int   rankS[256];
  __shared__ int   wsum[4];

  // ---- block 0 packs weights q-blocked f16 into ws (for k_main) ----
  if (bid==0){
    for (int i=tid;i<2048;i+=512){
      int qb=i>>7, r7=i&127, t=r7>>2, i2=r7&3, q=4*qb+i2;
      packW[i] = h2bits(mk2(We[(2*q)*32+t], We[(2*q+1)*32+t]));
    }
    for (int i=tid;i<512; i+=512){
      int qb=i>>7, r7=i&127, t=r7>>2, i2=r7&3, q=4*qb+i2;
      packW[2048+i] = h2bits(mk2(Wa[(2*q)*32+t], Wa[(2*q+1)*32+t]));
    }
    for (int i=tid;i<768; i+=512){
      int qb=i>>6, r6=i&63, tc=r6>>2, i2=r6&3, q=4*qb+i2;
      packW[2560+i] = h2bits(mk2(W0[(2*q)*16+tc], W0[(2*q+1)*16+tc]));
    }
    if (tid<192){
      int qb=tid/48, r48=tid%48, tc=r48>>2, i2=r48&3, q=4*qb+i2;
      float lo = (tc<3)? Wc1[(2*q)*3+tc]   : Wc2[(2*q)*9+(tc-3)];
      float hi = (tc<3)? Wc1[(2*q+1)*3+tc] : Wc2[(2*q+1)*9+(tc-3)];
      packW[3328+tid] = h2bits(mk2(lo,hi));
    }
    if (tid<32) ((float*)packW)[3520+tid] = Wa[32*32+tid];
  }

  // ---- msa LN: wave w rows w, w+8, w+16, w+24 ----
  const float gm = g_msa[lane], bm = b_msa[lane];
  for (int nn=w; nn<32; nn+=8){
    float x = msa[(size_t)(((b*32+nn)<<8)+(bid&255))*64 + lane];
    float s = wred64(x), s2 = wred64(x*x);
    float mu = s*(1.f/64.f);
    float var = s2*(1.f/64.f) - mu*mu;
    mn[nn][lane] = (x-mu)*rsqrtf(var+EPSLN)*gm + bm;
  }
  __syncthreads();
  // ---- q[e=lane]: partial over d-range per wave ----
  {
    float p = (w==0)? bq[lane] : 0.f;
    for (int d=w*8; d<w*8+8; d++) p += mn[0][d]*Wq[d*64+lane];
    redS[w][lane] = p;
  }
  __syncthreads();
  if (w==0){
    float q = 0.f;
    #pragma unroll
    for (int k=0;k<8;k++) q += redS[k][lane];
    qS[lane] = q*0.125f;               // 1/sqrt(64)
  }
  __syncthreads();
  // ---- qk[d=lane]: partial over e-range per wave ----
  {
    float p = 0.f;
    for (int e=w*8; e<w*8+8; e++) p += Wk[lane*64+e]*qS[e];
    redS[w][lane] = p;
  }
  __syncthreads();
  float qk = 0.f;
  #pragma unroll
  for (int k=0;k<8;k++) qk += redS[k][lane];
  const float qb_ = wred64(qS[lane]*bk[lane]);
  // ---- scores: wave w rows w*4..w*4+3 ----
  for (int nn=w*4; nn<w*4+4; nn++){
    float p = wred64(mn[nn][lane]*qk);
    if (lane==0) scS[nn] = p + qb_;
  }
  __syncthreads();
  // ---- softmax + weighted msa ----
  float mx = -1e30f;
  for (int nn=0; nn<32; nn++) mx = fmaxf(mx, scS[nn]);
  float ps=0.f, pm=0.f;
  for (int nn=w*4; nn<w*4+4; nn++){
    float e = expf(scS[nn]-mx);
    ps += e; pm += e*mn[nn][lane];
  }
  redS[w][lane] = pm;
  if (lane==0) ssumS[w] = ps;
  __syncthreads();
  if (w==0){
    float ssum = 0.f, acc = 0.f;
    #pragma unroll
    for (int k=0;k<8;k++){ ssum += ssumS[k]; acc += redS[k][lane]; }
    qS[lane] = acc / ssum;
  }
  __syncthreads();
  if (tid<32){
    float acc = bx[tid];
    for (int k=0;k<64;k++) acc += qS[k]*Wx[k*32+tid];
    const float* s1 = &seq1hot[bid*21];
    for (int k=0;k<21;k++) acc += s1[k]*Wx[(64+k)*32+tid];
    float s = wred32(acc), s2 = wred32(acc*acc);
    float mu = s*(1.f/32.f), var = s2*(1.f/32.f)-mu*mu;
    float v = (acc-mu)*rsqrtf(var+EPSLN)*g_node[tid] + b_node[tid];
    node[bid*32+tid] = v;
    nodeS[tid] = v;
  }
  __syncthreads();
  if (tid<16){
    float acc = b0[tid];
    for (int k=0;k<32;k++) acc += nodeS[k]*W0[(32+k)*16+tid];
    m0bG[bid*16+tid] = acc;
  }

  // --- Phase 2: distances + split rank scan (both halves) + compaction ---
  const bool act = tid < 256;
  const int i = bid & 255;
  const int j8 = tid & 255;            // j for this thread (both halves share j8)
  float D = 0.f;
  if (act){
    const float cax = xyz[(bid*3+1)*3+0];
    const float cay = xyz[(bid*3+1)*3+1];
    const float caz = xyz[(bid*3+1)*3+2];
    const int jb = (b<<8)+j8;
    float dx = xyz[(jb*3+1)*3+0]-cax;
    float dy = xyz[(jb*3+1)*3+1]-cay;
    float dz = xyz[(jb*3+1)*3+2]-caz;
    D = sqrtf(dx*dx+dy*dy+dz*dz) + (i==j8 ? 999.9f : 0.f);
  }
  __syncthreads();
  if (act) Dv[j8] = D;
  __syncthreads();
  // both halves scan half the Dv range for the same j8
  {
    const float Dj = Dv[j8];
    const int base = (tid >> 8) * 128;     // 0 for lower half, 128 for upper half
    int rank = 0;
    for (int j2=base; j2<base+128; j2+=4){
      const float4 dv = *(const float4*)&Dv[j2];
      rank += (dv.x < Dj || (dv.x == Dj && (j2+0) < j8)) ? 1 : 0;
      rank += (dv.y < Dj || (dv.y == Dj && (j2+1) < j8)) ? 1 : 0;
      rank += (dv.z < Dj || (dv.z == Dj && (j2+2) < j8)) ? 1 : 0;
      rank += (dv.w < Dj || (dv.w == Dj && (j2+3) < j8)) ? 1 : 0;
    }
    if (!act) rankS[j8] = rank;            // upper half deposits its partial
    else      wsum[0] = wsum[0];           // no-op keep structure
    if (act)  Dv[j8] = __int_as_float(rank); // stash lower partial in Dv slot (reused)
  }
  __syncthreads();
  if (act){
    const int rank = __float_as_int(Dv[j8]) + rankS[j8];
    int K = topk[0];
    if (K<=0 || K>256){
      float f = ((const float*)topk)[0];
      K = (f>=1.f && f<=256.f) ? (int)f : 64;
    }
    const int jb = (b<<8)+j8;
    const int sep = abs(idxp[jb] - idxp[bid]);
    const bool m = (rank < K) || (i!=j8 && sep < KMINC);
    unsigned long long bal = __ballot(m);
    const int l6 = j8 & 63, wv = j8 >> 6;
    const int pre = __popcll(bal & ((1ull<<l6)-1ull));
    if (l6==0) wsum[wv] = __popcll(bal);
    __syncthreads();
    int off = 0;
    for (int w2=0;w2<wv;w2++) off += wsum[w2];
    if (m) jlist[bid*96 + off + pre] = j8;
    if (j8==0) cnt[bid] = wsum[0]+wsum[1]+wsum[2]+wsum[3];
  } else {
    __syncthreads();
  }
}

// ---------------- Kernel C: wave-per-slice gathered pipeline, b128 LDS (r17-verified) ----------------
// grid = 512*SLI/4 (1280), block = 256 = 4 independent waves; wave = one 8-row slice.
__global__ __launch_bounds__(256) void k_main(
    const float* __restrict__ pair, const float* __restrict__ xyz,
    const float* __restrict__ g_pair, const float* __restrict__ b_pair,
    const float* __restrict__ be, const float* __restrict__ g_edge,
    const float* __restrict__ b_edge, const float* __restrict__ ba,
    const float* __restrict__ node, const int* __restrict__ cnt,
    const int* __restrict__ jlist, const float* __restrict__ m0bG,
    const unsigned* __restrict__ packW, float* __restrict__ part)
{
  const int tid = threadIdx.x;
  const int w  = tid >> 6;          // wave 0..3
  const int wl = tid & 63;          // lane in wave
  const int r  = (tid >> 5) & 1;    // group in wave
  const int t  = tid & 31;          // lane in group

  __shared__ alignas(16) unsigned WeL[2048];        // 8 KB q-blocked
  __shared__ alignas(16) unsigned WaL[512];         // 2 KB
  __shared__ alignas(16) unsigned W0L[768];         // 3 KB
  __shared__ alignas(16) unsigned WcL[192];         // 768 B
  __shared__ float waD[32];
  __shared__ float beS[32], geS[32], beeS[32], baS[32];
  __shared__ alignas(16) _Float16 pnH[32][128];     // 8 KB
  __shared__ alignas(16) _Float16 edH[32][32];      // 2 KB
  __shared__ alignas(16) _Float16 aH [32][32];      // 2 KB
  __shared__ alignas(16) _Float16 ndH[32][32];      // 2 KB
  __shared__ float cS[32*12];
  __shared__ float xjS[32][9];
  __shared__ float geoS[32][4];

  // ---- vectorized weight copy (uint4) ----
  {
    const uint4* p4 = (const uint4*)packW;
    #pragma unroll
    for (int i2=tid;i2<512;i2+=256) ((uint4*)WeL)[i2] = p4[i2];
    if (tid<128) ((uint4*)WaL)[tid] = p4[512+tid];
    if (tid<192) ((uint4*)W0L)[tid] = p4[640+tid];
    if (tid<48)  ((uint4*)WcL)[tid] = p4[832+tid];
  }
  if (tid<32){
    waD[tid] = ((const float*)packW)[3520+tid];
    beS[tid]=be[tid]; geS[tid]=g_edge[tid]; beeS[tid]=b_edge[tid]; baS[tid]=ba[tid];
  }
  __syncthreads();        // the ONLY block-wide barrier

  const int s    = blockIdx.x*4 + w;   // slice id
  const int item = s / SLI;            // (b,i)
  const int sl   = s - item*SLI;
  const int b    = item >> 8;
  const int n    = cnt[item];
  const int row0 = sl*8;
  const int wrow = w*8;

  float stA = 0.f;
  float ofA = 0.f;

  if (row0 < n){
    const float cax = xyz[(item*3+1)*3+0];
    const float cay = xyz[(item*3+1)*3+1];
    const float caz = xyz[(item*3+1)*3+2];
    bool vals[4];
    // ---- stage 4 rows per group ----
    {
      const float4 gp4 = *(const float4*)&g_pair[4*t];
      const float4 bp4 = *(const float4*)&b_pair[4*t];
      #pragma unroll
      for (int jc=0;jc<4;jc++){
        const int slot = row0 + r*4 + jc;
        vals[jc] = slot < n;
        const int jj = vals[jc] ? jlist[item*96 + slot] : 0;
        const int row = wrow + r*4 + jc;
        const float* prow = &pair[((long)item*256 + jj)*128];
        const float4 pv4 = *(const float4*)&prow[4*t];
        float sm  = wred32(pv4.x+pv4.y+pv4.z+pv4.w);
        float sm2 = wred32(pv4.x*pv4.x+pv4.y*pv4.y+pv4.z*pv4.z+pv4.w*pv4.w);
        float mu = sm*(1.f/128.f);
        float var = sm2*(1.f/128.f)-mu*mu;
        float rs = rsqrtf(var+EPSLN);
        h4 o;
        o[0]=(_Float16)((pv4.x-mu)*rs*gp4.x+bp4.x);
        o[1]=(_Float16)((pv4.y-mu)*rs*gp4.y+bp4.y);
        o[2]=(_Float16)((pv4.z-mu)*rs*gp4.z+bp4.z);
        o[3]=(_Float16)((pv4.w-mu)*rs*gp4.w+bp4.w);
        *(h4*)&pnH[row][4*t] = o;
        const int jb=(b<<8)+jj;
        ndH[row][t] = (_Float16)node[jb*32+t];
        if (t<9) xjS[row][t] = xyz[(size_t)jb*9 + t];
        if (t==0){
          float jx = xyz[(size_t)jb*9+3]-cax;
          float jy = xyz[(size_t)jb*9+4]-cay;
          float jz = xyz[(size_t)jb*9+5]-caz;
          geoS[row][0]=jx; geoS[row][1]=jy; geoS[row][2]=jz;
          geoS[row][3]=sqrtf(jx*jx+jy*jy+jz*jz);
        }
      }
    }
    // ---- edge GEMV (128->32): 16 iters, all-b128 ----
    float ea0[4], ea1[4];
    #pragma unroll
    for (int jc=0;jc<4;jc++){ ea0[jc]=beS[t]; ea1[jc]=0.f; }
    for (int qb=0; qb<16; ++qb){
      const uint4 wv = *(const uint4*)&WeL[qb*128 + t*4];
      #pragma unroll
      for (int jc=0;jc<4;jc++){
        const uint4 pv = *(const uint4*)&pnH[wrow + r*4 + jc][8*qb];
        ea0[jc]=FDOT2(asH2(wv.y), asH2(pv.y), FDOT2(asH2(wv.x), asH2(pv.x), ea0[jc]));
        ea1[jc]=FDOT2(asH2(wv.w), asH2(pv.w), FDOT2(asH2(wv.z), asH2(pv.z), ea1[jc]));
      }
    }
    // ---- edge LN -> edH f16 ----
    #pragma unroll
    for (int jc=0;jc<4;jc++){
      float acc=ea0[jc]+ea1[jc];
      float sm=wred32(acc), sm2=wred32(acc*acc);
      float mu=sm*(1.f/32.f), var=sm2*(1.f/32.f)-mu*mu;
      edH[wrow + r*4 + jc][t] = (_Float16)((acc-mu)*rsqrtf(var+EPSLN)*geS[t]+beeS[t]);
    }
    // ---- a = relu([edge, dist] @ Wa + ba) ----
    float av[4];
    #pragma unroll
    for (int jc=0;jc<4;jc++) av[jc]=baS[t]+geoS[wrow + r*4 + jc][3]*waD[t];
    for (int qb=0; qb<4; ++qb){
      const uint4 wv = *(const uint4*)&WaL[qb*128 + t*4];
      #pragma unroll
      for (int jc=0;jc<4;jc++){
        const uint4 ev = *(const uint4*)&edH[wrow + r*4 + jc][8*qb];
        av[jc]=FDOT2(asH2(wv.w), asH2(ev.w), FDOT2(asH2(wv.z), asH2(ev.z),
                FDOT2(asH2(wv.y), asH2(ev.y), FDOT2(asH2(wv.x), asH2(ev.x), av[jc]))));
      }
    }
    #pragma unroll
    for (int jc=0;jc<4;jc++) aH[wrow + r*4 + jc][t]=(_Float16)fmaxf(av[jc],0.f);
    // ---- m0: a-part lanes t<16 (W0 blocks 0..3), node-part t>=16 (blocks 8..11) ----
    {
      const int half = t>>4, tc = t&15;
      const int wb = half ? 8 : 0;
      const float m0b = half ? 0.f : m0bG[item*16+tc];
      float m0v[4];
      #pragma unroll
      for (int jc=0;jc<4;jc++) m0v[jc]=m0b;
      for (int qb=0;qb<4;++qb){
        const uint4 wv = *(const uint4*)&W0L[(wb+qb)*64 + tc*4];
        #pragma unroll
        for (int jc=0;jc<4;jc++){
          const _Float16* opb = half ? &ndH[wrow + r*4 + jc][0] : &aH[wrow + r*4 + jc][0];
          const uint4 ov = *(const uint4*)&opb[8*qb];
          m0v[jc]=FDOT2(asH2(wv.w), asH2(ov.w), FDOT2(asH2(wv.z), asH2(ov.z),
                   FDOT2(asH2(wv.y), asH2(ov.y), FDOT2(asH2(wv.x), asH2(ov.x), m0v[jc]))));
        }
      }
      #pragma unroll
      for (int jc=0;jc<4;jc++){
        float tot = m0v[jc] + __shfl_xor(m0v[jc], 16);
        if (t<16 && vals[jc]) stA += fmaxf(tot, 0.f);
      }
    }
    // ---- c1/c2 from a: lanes t<12 k-rows 0..15 (blocks 0..1), lanes 12..23 k 16..31 (blocks 2..3) ----
    {
      const bool up = (t>=12 && t<24);
      const int tc12 = up ? t-12 : (t<12 ? t : 0);
      const int wb = up ? 2 : 0;
      const int koff = up ? 16 : 0;
      float cv[4]={0.f,0.f,0.f,0.f};
      for (int qb=0;qb<2;++qb){
        const uint4 wv = *(const uint4*)&WcL[(wb+qb)*48 + tc12*4];
        #pragma unroll
        for (int jc=0;jc<4;jc++){
          const uint4 av2 = *(const uint4*)&aH[wrow + r*4 + jc][koff + 8*qb];
          cv[jc]=FDOT2(asH2(wv.w), asH2(av2.w), FDOT2(asH2(wv.z), asH2(av2.z),
                  FDOT2(asH2(wv.y), asH2(av2.y), FDOT2(asH2(wv.x), asH2(av2.x), cv[jc]))));
        }
      }
      #pragma unroll
      for (int jc=0;jc<4;jc++){
        const int src = (t<12) ? t+12 : (up ? t-12 : t);
        float other = __shfl(cv[jc], src, 32);
        if (t<12) cS[(wrow + r*4 + jc)*12+t] = cv[jc]+other;
      }
    }
    // ---- offset accumulation (t<9) ----
    if (t<9){
      const int o=t/3, x=t-o*3;
      #pragma unroll
      for (int jc=0;jc<4;jc++){
        if (!vals[jc]) continue;
        const int row = wrow + r*4 + jc;
        const float dj = geoS[row][3];
        const float dh = geoS[row][x]/(dj+1e-8f);
        const float* cr = &cS[row*12];
        float val = cr[o]*dh;
        const float caxj = xjS[row][3+x];
        #pragma unroll
        for (int c=0;c<3;c++){
          val += cr[3+o*3+c]*(xjS[row][c*3+x]-caxj);
        }
        ofA += val;
      }
    }
  }

  stA += __shfl_xor(stA, 32);
  ofA += __shfl_xor(ofA, 32);
  if (wl < 16) part[s*28 + wl] = stA;
  if (wl < 9)  part[s*28 + 16 + wl] = ofA;
}

// ---------------- Kernel F: combine partials, scale by deg, form xyz_new ----------------
// grid = B*L (512), block = 64
__global__ __launch_bounds__(64) void k_fin(
    const float* __restrict__ xyz, const int* __restrict__ cnt,
    const float* __restrict__ part, float* __restrict__ out)
{
  const int bid = blockIdx.x;
  const int t = threadIdx.x;
  __shared__ float offF[9];
  const int n = cnt[bid];
  const float invd = 1.f/fmaxf((float)n,1.f);
  if (t<16){
    float s=0.f;
    #pragma unroll
    for (int k2=0;k2<SLI;k2++) s += part[(bid*SLI+k2)*28 + t];
    out[4608 + bid*16 + t] = s*invd;           // state
  } else if (t<25){
    float s=0.f;
    #pragma unroll
    for (int k2=0;k2<SLI;k2++) s += part[(bid*SLI+k2)*28 + t];
    offF[t-16] = s*invd;
  }
  __syncthreads();
  if (t<9){
    const int o=t/3, x=t-o*3;
    const float cac = xyz[(bid*3+1)*3+x];
    const float CA = cac + offF[3+x];          // offset[:,:,1]
    const float v = (o==1)? CA : (CA + offF[o*3+x]);
    out[bid*9 + t] = v;                        // xyz_new
  }
}

extern "C" void kernel_launch(void* const* d_in, const int* in_sizes, int n_in,
                              void* d_out, int out_size, void* d_ws, size_t ws_size,
                              hipStream_t stream)
{
  const float* msa     = (const float*)d_in[0];
  const float* pair    = (const float*)d_in[1];
  const float* xyz     = (const float*)d_in[2];
  const float* seq1hot = (const float*)d_in[3];
  const float* g_msa   = (const float*)d_in[4];
  const float* b_msa   = (const float*)d_in[5];
  const float* g_pair  = (const float*)d_in[6];
  const float* b_pair  = (const float*)d_in[7];
  const float* Wq      = (const float*)d_in[8];
  const float* bq      = (const float*)d_in[9];
  const float* Wk      = (const float*)d_in[10];
  const float* bk      = (const float*)d_in[11];
  const float* Wx      = (const float*)d_in[12];
  const float* bx      = (const float*)d_in[13];
  const float* g_node  = (const float*)d_in[14];
  const float* b_node  = (const float*)d_in[15];
  const float* We      = (const float*)d_in[16];
  const float* be      = (const float*)d_in[17];
  const float* g_edge  = (const float*)d_in[18];
  const float* b_edge  = (const float*)d_in[19];
  const float* Wa      = (const float*)d_in[20];
  const float* ba      = (const float*)d_in[21];
  const float* W0      = (const float*)d_in[22];
  const float* b0      = (const float*)d_in[23];
  const float* Wc1     = (const float*)d_in[24];
  const float* Wc2     = (const float*)d_in[25];
  const int*   idx     = (const int*)d_in[26];
  const int*   topk    = (const int*)d_in[27];
  float* out = (float*)d_out;

  float* wsf = (float*)d_ws;
  float*    node  = wsf + WS_NODE;
  int*      cnt   = (int*)(wsf + WS_CNT);
  int*      jlist = (int*)(wsf + WS_JLIST);
  float*    m0bG  = wsf + WS_M0B;
  float*    partb = wsf + WS_PART;
  unsigned* packW = (unsigned*)(wsf + WS_PACKW);

  k_prep<<<512, 512, 0, stream>>>(msa, seq1hot, xyz, idx, topk, g_msa, b_msa,
                                  Wq, bq, Wk, bk, Wx, bx, g_node, b_node,
                                  We, Wa, W0, b0, Wc1, Wc2,
                                  node, cnt, jlist, m0bG, packW);
  k_main<<<512*SLI/4, 256, 0, stream>>>(pair, xyz, g_pair, b_pair, be, g_edge,
                                        b_edge, ba, node, cnt, jlist, m0bG,
                                        packW, partb);
  k_fin<<<512, 64, 0, stream>>>(xyz, cnt, partb, out);
}